// Round 4
// baseline (498.872 us; speedup 1.0000x reference)
//
#include <hip/hip_runtime.h>
#include <hip/hip_bf16.h>

#define N_NODES 50000
#define N_EDGES 800000
#define N_GRAPHS 512
#define DIM 256
#define LN_EPS 1e-5f

typedef __attribute__((ext_vector_type(8))) short bf16x8;
typedef __attribute__((ext_vector_type(4))) float f32x4;
typedef __attribute__((ext_vector_type(8))) ushort ushort8;

__device__ __forceinline__ float bf2f(ushort u) {
    union { float f; unsigned int i; } c;
    c.i = ((unsigned int)u) << 16;
    return c.f;
}
__device__ __forceinline__ ushort f2bf(float f) {
    union { float f; unsigned int i; } c;
    c.f = f;
    unsigned int r = (c.i + 0x7fffu + ((c.i >> 16) & 1u)) >> 16;
    return (ushort)r;
}
__device__ __forceinline__ float4 b2f4(ushort4 v) {
    return make_float4(bf2f(v.x), bf2f(v.y), bf2f(v.z), bf2f(v.w));
}

// async global -> LDS, 16B per lane. lds base must be wave-uniform; HW adds lane*16.
__device__ __forceinline__ void async16(const ushort* g, ushort* l) {
    __builtin_amdgcn_global_load_lds(
        (const __attribute__((address_space(1))) unsigned int*)g,
        (__attribute__((address_space(3))) unsigned int*)l,
        16, 0, 0);
}

// -------------------- CSR build --------------------

__global__ void k_hist(const int* __restrict__ dst, int* __restrict__ cnt) {
    int e = blockIdx.x * blockDim.x + threadIdx.x;
    if (e < N_EDGES) atomicAdd(&cnt[dst[e]], 1);
}

__global__ __launch_bounds__(256) void k_scan1(const int* __restrict__ cnt,
                                               int* __restrict__ row_ptr,
                                               int* __restrict__ bsum) {
    __shared__ int sd[256];
    int t = threadIdx.x, b = blockIdx.x;
    int base = b * 2048 + t * 8;
    int v[8];
    int tot = 0;
#pragma unroll
    for (int j = 0; j < 8; ++j) {
        int i = base + j;
        int c = (i < N_NODES) ? cnt[i] : 0;
        v[j] = tot;
        tot += c;
    }
    sd[t] = tot;
    __syncthreads();
    for (int off = 1; off < 256; off <<= 1) {
        int x = (t >= off) ? sd[t - off] : 0;
        __syncthreads();
        sd[t] += x;
        __syncthreads();
    }
    int excl = sd[t] - tot;
#pragma unroll
    for (int j = 0; j < 8; ++j) {
        int i = base + j;
        if (i < N_NODES) row_ptr[i] = excl + v[j];
    }
    if (t == 255) bsum[b] = sd[255];
}

// single wave, shuffle prefix scan over <=64 block sums
__global__ void k_scan2(int* __restrict__ bsum, int nb) {
    int l = threadIdx.x;
    int v = (l < nb) ? bsum[l] : 0;
    int s = v;
#pragma unroll
    for (int off = 1; off < 64; off <<= 1) {
        int u = __shfl_up(s, off);
        if (l >= off) s += u;
    }
    if (l < nb) bsum[l] = s - v;  // exclusive
}

// finalize row_ptr, init cursor, compute dinv (fused)
__global__ void k_scan3(const int* __restrict__ bsum, const int* __restrict__ cnt,
                        int* __restrict__ row_ptr, int* __restrict__ cursor,
                        float* __restrict__ dinv) {
    int i = blockIdx.x * blockDim.x + threadIdx.x;
    if (i < N_NODES) {
        int v = row_ptr[i] + bsum[i >> 11];
        row_ptr[i] = v;
        cursor[i] = v;
        dinv[i] = rsqrtf((float)cnt[i] + 1.0f);
    }
    if (i == 0) row_ptr[N_NODES] = N_EDGES;
}

__global__ void k_scatter(const int* __restrict__ src, const int* __restrict__ dst,
                          const float* __restrict__ dinv, int* __restrict__ cursor,
                          int* __restrict__ csr_src, float* __restrict__ csr_w) {
    int e = blockIdx.x * blockDim.x + threadIdx.x;
    if (e < N_EDGES) {
        int s = src[e], d = dst[e];
        int pos = atomicAdd(&cursor[d], 1);
        csr_src[pos] = s;
        csr_w[pos] = dinv[s] * dinv[d];
    }
}

// -------------------- weight transpose + bf16 cast (all 3 layers, one launch) --------------------

__global__ __launch_bounds__(256) void k_wt3(const float* __restrict__ W0,
                                             const float* __restrict__ W1,
                                             const float* __restrict__ W2,
                                             ushort* __restrict__ Wt) {
    int l = blockIdx.x >> 4;
    const float* W = (l == 0) ? W0 : (l == 1) ? W1 : W2;
    ushort* o = Wt + (size_t)l * DIM * DIM;
    int t = threadIdx.x;
    int kbase = (blockIdx.x & 15) * 16;
    for (int kk = 0; kk < 16; ++kk) {
        int k = kbase + kk;
        o[(size_t)t * DIM + k] = f2bf(W[(size_t)k * DIM + t]);
    }
}

// -------------------- fp32 -> bf16 convert --------------------

__global__ __launch_bounds__(256) void k_xcvt(const float* __restrict__ x, ushort* __restrict__ o) {
    int i = blockIdx.x * blockDim.x + threadIdx.x;
    const size_t total4 = (size_t)N_NODES * DIM / 4;
    if ((size_t)i < total4) {
        float4 v = *(const float4*)(x + (size_t)i * 4);
        ushort4 u;
        u.x = f2bf(v.x); u.y = f2bf(v.y); u.z = f2bf(v.z); u.w = f2bf(v.w);
        *(ushort4*)(o + (size_t)i * 4) = u;
    }
}

// -------------------- bf16 MFMA GEMM: H[M x 256] = A[M x 256] @ W[256 x 256] --------------------
// A bf16 row-major, Wt bf16 [n][k]. Tile 128x256 (full width), BK=32, 4 waves.
// Linear LDS 64B rows + global_load_lds width-16 staging (m97 structure).

#define GBM 128
#define GBK 32

__global__ __launch_bounds__(256) void k_gemm(const ushort* __restrict__ A,
                                              const ushort* __restrict__ Wt,
                                              ushort* __restrict__ H, int M) {
    __shared__ ushort As[GBM * GBK];        // 8 KB
    __shared__ ushort Bs[DIM * GBK];        // 16 KB
    int t = threadIdx.x;
    int lane = t & 63;
    int w = t >> 6;
    int wm = w >> 1, wn = w & 1;            // wave tile: rows wm*64..+63, cols wn*128..+127
    int bm0 = blockIdx.x * GBM;

    f32x4 acc[4][8];
#pragma unroll
    for (int m = 0; m < 4; ++m)
#pragma unroll
        for (int n = 0; n < 8; ++n) acc[m][n] = (f32x4)0.0f;

    int fr = lane & 15;
    int fq = lane >> 4;
    int lr = lane >> 2;         // row within 16-row staging chunk
    int lc = (lane & 3) * 8;    // ushort col within 32

    for (int k0 = 0; k0 < DIM; k0 += GBK) {
        // A: 8 chunks of 16 rows (1KB each); wave w takes chunks w and w+4
#pragma unroll
        for (int p = 0; p < 2; ++p) {
            int rb = (w + p * 4) * 16;
            int ga = bm0 + rb + lr;
            if (ga > M - 1) ga = M - 1;
            async16(A + (size_t)ga * DIM + k0 + lc, &As[rb * GBK]);
        }
        // B: 16 chunks; wave w takes chunks w*4 .. w*4+3
#pragma unroll
        for (int p = 0; p < 4; ++p) {
            int rb = (w * 4 + p) * 16;
            async16(Wt + (size_t)(rb + lr) * DIM + k0 + lc, &Bs[rb * GBK]);
        }
        __syncthreads();
        bf16x8 af[4], bfv[8];
#pragma unroll
        for (int m = 0; m < 4; ++m)
            af[m] = *(const bf16x8*)&As[(wm * 64 + m * 16 + fr) * GBK + fq * 8];
#pragma unroll
        for (int n = 0; n < 8; ++n)
            bfv[n] = *(const bf16x8*)&Bs[(wn * 128 + n * 16 + fr) * GBK + fq * 8];
#pragma unroll
        for (int m = 0; m < 4; ++m)
#pragma unroll
            for (int n = 0; n < 8; ++n)
                acc[m][n] = __builtin_amdgcn_mfma_f32_16x16x32_bf16(af[m], bfv[n], acc[m][n], 0, 0, 0);
        __syncthreads();
    }
    // D row = (lane>>4)*4 + j, col = lane&15  [m89-verified]
#pragma unroll
    for (int m = 0; m < 4; ++m) {
        int row0 = bm0 + wm * 64 + m * 16 + fq * 4;
#pragma unroll
        for (int n = 0; n < 8; ++n) {
            int col = wn * 128 + n * 16 + fr;
#pragma unroll
            for (int j = 0; j < 4; ++j) {
                int row = row0 + j;
                if (row < M) H[(size_t)row * DIM + col] = f2bf(acc[m][n][j]);
            }
        }
    }
}

// -------------------- aggregation + bias + LayerNorm + ReLU (bf16 in/out) --------------------
// 2 nodes/block, 2 waves/node (edge list split), 4 cols/lane, edge loop x4 unrolled.

#define FMA4(A, W, V) { float4 _f = b2f4(V); A.x += (W)*_f.x; A.y += (W)*_f.y; A.z += (W)*_f.z; A.w += (W)*_f.w; }

__global__ __launch_bounds__(256) void k_agg_ln(const ushort* __restrict__ h,
                                                const int* __restrict__ rp,
                                                const int* __restrict__ cs,
                                                const float* __restrict__ cw,
                                                const float* __restrict__ dinv,
                                                const float* __restrict__ bias,
                                                const float* __restrict__ gamma,
                                                const float* __restrict__ beta,
                                                ushort* __restrict__ out) {
    __shared__ float4 part[2][64];
    int t = threadIdx.x;
    int w = t >> 6;
    int nib = w >> 1;                 // node in block (0/1)
    int half = w & 1;                 // edge-range half
    int node = (blockIdx.x << 1) + nib;
    int lane = t & 63;
    int c0 = lane << 2;

    float4 a0 = make_float4(0.f, 0.f, 0.f, 0.f);
    float4 a1 = a0, a2 = a0, a3 = a0;

    if (half == 0) {
        float di = dinv[node];
        float sw = di * di;
        ushort4 hv = *(const ushort4*)(h + (size_t)node * DIM + c0);
        float4 f = b2f4(hv);
        a0 = make_float4(f.x * sw, f.y * sw, f.z * sw, f.w * sw);
    }

    int e0 = rp[node], e1 = rp[node + 1];
    int mid = e0 + ((e1 - e0 + 1) >> 1);
    int es = half ? mid : e0;
    int ee = half ? e1 : mid;

    for (int e = es; e < ee; e += 4) {
        int s0 = cs[e];
        float w0 = cw[e];
        int s1 = 0, s2 = 0, s3 = 0;
        float w1 = 0.f, w2 = 0.f, w3 = 0.f;
        if (e + 1 < ee) { s1 = cs[e + 1]; w1 = cw[e + 1]; }
        if (e + 2 < ee) { s2 = cs[e + 2]; w2 = cw[e + 2]; }
        if (e + 3 < ee) { s3 = cs[e + 3]; w3 = cw[e + 3]; }
        ushort4 v0 = *(const ushort4*)(h + (size_t)s0 * DIM + c0);
        ushort4 v1 = *(const ushort4*)(h + (size_t)s1 * DIM + c0);
        ushort4 v2 = *(const ushort4*)(h + (size_t)s2 * DIM + c0);
        ushort4 v3 = *(const ushort4*)(h + (size_t)s3 * DIM + c0);
        FMA4(a0, w0, v0);
        FMA4(a1, w1, v1);
        FMA4(a2, w2, v2);
        FMA4(a3, w3, v3);
    }

    float4 v;
    v.x = (a0.x + a1.x) + (a2.x + a3.x);
    v.y = (a0.y + a1.y) + (a2.y + a3.y);
    v.z = (a0.z + a1.z) + (a2.z + a3.z);
    v.w = (a0.w + a1.w) + (a2.w + a3.w);

    if (half == 1) part[nib][lane] = v;
    __syncthreads();
    if (half == 1) return;

    float4 o = part[nib][lane];
    float4 bi = *(const float4*)(bias + c0);
    v.x += o.x + bi.x;
    v.y += o.y + bi.y;
    v.z += o.z + bi.z;
    v.w += o.w + bi.w;

    float s1v = v.x + v.y + v.z + v.w;
    float s2v = v.x * v.x + v.y * v.y + v.z * v.z + v.w * v.w;
#pragma unroll
    for (int off = 1; off < 64; off <<= 1) {
        s1v += __shfl_xor(s1v, off);
        s2v += __shfl_xor(s2v, off);
    }
    float mu = s1v * (1.0f / DIM);
    float var = s2v * (1.0f / DIM) - mu * mu;
    float rstd = rsqrtf(var + LN_EPS);

    float4 g = *(const float4*)(gamma + c0);
    float4 be = *(const float4*)(beta + c0);
    ushort4 ov;
    ov.x = f2bf(fmaxf((v.x - mu) * rstd * g.x + be.x, 0.f));
    ov.y = f2bf(fmaxf((v.y - mu) * rstd * g.y + be.y, 0.f));
    ov.z = f2bf(fmaxf((v.z - mu) * rstd * g.z + be.z, 0.f));
    ov.w = f2bf(fmaxf((v.w - mu) * rstd * g.w + be.w, 0.f));
    *(ushort4*)(out + (size_t)node * DIM + c0) = ov;
}

// -------------------- pooling --------------------

__global__ void k_gbound(const int* __restrict__ batch, int* __restrict__ gstart) {
    int n = blockIdx.x * blockDim.x + threadIdx.x;
    if (n >= N_NODES) return;
    int bc = batch[n];
    int bp = (n == 0) ? -1 : batch[n - 1];
    for (int g = bp + 1; g <= bc; ++g) gstart[g] = n;
    if (n == N_NODES - 1)
        for (int g = bc + 1; g <= N_GRAPHS; ++g) gstart[g] = N_NODES;
}

__global__ __launch_bounds__(256) void k_pool(const ushort* __restrict__ x,
                                              const int* __restrict__ gstart,
                                              float* __restrict__ pooled) {
    int g = blockIdx.x, d = threadIdx.x;
    int r0 = gstart[g], r1 = gstart[g + 1];
    float s = 0.f;
    for (int r = r0; r < r1; ++r) s += bf2f(x[(size_t)r * DIM + d]);
    float c = (float)(r1 - r0);
    pooled[(size_t)g * DIM + d] = s / fmaxf(c, 1.0f);
}

// -------------------- final FC: out = relu(pooled @ fc_w^T + fc_b) --------------------
#define GB 16
__global__ __launch_bounds__(256) void k_fc(const float* __restrict__ pooled,
                                            const float* __restrict__ fcw,
                                            const float* __restrict__ fcb,
                                            float* __restrict__ out) {
    __shared__ float pl[GB][DIM];
    int j = threadIdx.x;
    int g0 = blockIdx.x * GB;
#pragma unroll
    for (int r = 0; r < GB; ++r) pl[r][j] = pooled[(size_t)(g0 + r) * DIM + j];
    __syncthreads();
    float acc[GB];
    float bj = fcb[j];
#pragma unroll
    for (int r = 0; r < GB; ++r) acc[r] = bj;
    for (int k = 0; k < DIM; ++k) {
        float w = fcw[(size_t)j * DIM + k];
#pragma unroll
        for (int r = 0; r < GB; ++r) acc[r] += pl[r][k] * w;
    }
#pragma unroll
    for (int r = 0; r < GB; ++r) out[(size_t)(g0 + r) * DIM + j] = fmaxf(acc[r], 0.0f);
}

// -------------------- launch --------------------

extern "C" void kernel_launch(void* const* d_in, const int* in_sizes, int n_in,
                              void* d_out, int out_size, void* d_ws, size_t ws_size,
                              hipStream_t stream) {
    const float* x = (const float*)d_in[0];
    const int* ei = (const int*)d_in[1];
    const int* src = ei;
    const int* dst = ei + N_EDGES;
    const int* batch = (const int*)d_in[2];
    const float* W[3] = {(const float*)d_in[3], (const float*)d_in[7], (const float*)d_in[11]};
    const float* bs[3] = {(const float*)d_in[4], (const float*)d_in[8], (const float*)d_in[12]};
    const float* gs[3] = {(const float*)d_in[5], (const float*)d_in[9], (const float*)d_in[13]};
    const float* be[3] = {(const float*)d_in[6], (const float*)d_in[10], (const float*)d_in[14]};
    const float* fcw = (const float*)d_in[15];
    const float* fcb = (const float*)d_in[16];
    float* out = (float*)d_out;

    char* p = (char*)d_ws;
    auto alloc = [&](size_t bytes) {
        char* r = p;
        p += (bytes + 255) & ~(size_t)255;
        return r;
    };
    ushort* h       = (ushort*)alloc((size_t)N_NODES * DIM * 2);
    ushort* bufA    = (ushort*)alloc((size_t)N_NODES * DIM * 2);
    ushort* bufB    = (ushort*)alloc((size_t)N_NODES * DIM * 2);
    ushort* Wt      = (ushort*)alloc((size_t)3 * DIM * DIM * 2);
    int*   cnt     = (int*)alloc((size_t)N_NODES * 4);
    int*   row_ptr = (int*)alloc((size_t)(N_NODES + 1) * 4);
    int*   cursor  = (int*)alloc((size_t)N_NODES * 4);
    float* dinv    = (float*)alloc((size_t)N_NODES * 4);
    int*   csr_src = (int*)alloc((size_t)N_EDGES * 4);
    float* csr_w   = (float*)alloc((size_t)N_EDGES * 4);
    int*   bsum    = (int*)alloc(256 * 4);
    int*   gstart  = (int*)alloc((size_t)(N_GRAPHS + 1) * 4);
    float* pooled  = (float*)alloc((size_t)N_GRAPHS * DIM * 4);

    hipMemsetAsync(cnt, 0, (size_t)N_NODES * 4, stream);

    const int TPB = 256;
    int gridE = (N_EDGES + TPB - 1) / TPB;
    int gridN = (N_NODES + TPB - 1) / TPB;
    const int NB1 = (N_NODES + 2047) / 2048;  // 25

    k_wt3<<<48, TPB, 0, stream>>>(W[0], W[1], W[2], Wt);
    {
        int tot4 = N_NODES * DIM / 4;
        k_xcvt<<<(tot4 + TPB - 1) / TPB, TPB, 0, stream>>>(x, bufA);
    }

    k_hist<<<gridE, TPB, 0, stream>>>(dst, cnt);
    k_scan1<<<NB1, TPB, 0, stream>>>(cnt, row_ptr, bsum);
    k_scan2<<<1, 64, 0, stream>>>(bsum, NB1);
    k_scan3<<<gridN, TPB, 0, stream>>>(bsum, cnt, row_ptr, cursor, dinv);
    k_scatter<<<gridE, TPB, 0, stream>>>(src, dst, dinv, cursor, csr_src, csr_w);

    ushort* cur = bufA;
    ushort* nxt = bufB;
    for (int l = 0; l < 3; ++l) {
        int gg = (N_NODES + GBM - 1) / GBM;
        k_gemm<<<gg, TPB, 0, stream>>>(cur, Wt + (size_t)l * DIM * DIM, h, N_NODES);
        k_agg_ln<<<N_NODES / 2, TPB, 0, stream>>>(h, row_ptr, csr_src, csr_w, dinv,
                                                  bs[l], gs[l], be[l], nxt);
        ushort* tmp = cur; cur = nxt; nxt = tmp;
    }

    k_gbound<<<gridN, TPB, 0, stream>>>(batch, gstart);
    k_pool<<<N_GRAPHS, TPB, 0, stream>>>(cur, gstart, pooled);
    k_fc<<<N_GRAPHS / GB, TPB, 0, stream>>>(pooled, fcw, fcb, out);
}

// Round 5
// 428.877 us; speedup vs baseline: 1.1632x; 1.1632x over previous
//
#include <hip/hip_runtime.h>
#include <hip/hip_bf16.h>

#define N_NODES 50000
#define N_EDGES 800000
#define N_GRAPHS 512
#define DIM 256
#define LN_EPS 1e-5f

typedef __attribute__((ext_vector_type(8))) short bf16x8;
typedef __attribute__((ext_vector_type(4))) float f32x4;
typedef __attribute__((ext_vector_type(8))) ushort ushort8;

__device__ __forceinline__ float bf2f(ushort u) {
    union { float f; unsigned int i; } c;
    c.i = ((unsigned int)u) << 16;
    return c.f;
}
__device__ __forceinline__ ushort f2bf(float f) {
    union { float f; unsigned int i; } c;
    c.f = f;
    unsigned int r = (c.i + 0x7fffu + ((c.i >> 16) & 1u)) >> 16;
    return (ushort)r;
}

// async global -> LDS, 16B per lane. lds base must be wave-uniform; HW adds lane*16.
__device__ __forceinline__ void async16(const ushort* g, ushort* l) {
    __builtin_amdgcn_global_load_lds(
        (const __attribute__((address_space(1))) unsigned int*)g,
        (__attribute__((address_space(3))) unsigned int*)l,
        16, 0, 0);
}

// -------------------- CSR build --------------------

__global__ void k_hist(const int* __restrict__ dst, int* __restrict__ cnt) {
    int e = blockIdx.x * blockDim.x + threadIdx.x;
    if (e < N_EDGES) atomicAdd(&cnt[dst[e]], 1);
}

__global__ __launch_bounds__(256) void k_scan1(const int* __restrict__ cnt,
                                               int* __restrict__ row_ptr,
                                               int* __restrict__ bsum) {
    __shared__ int sd[256];
    int t = threadIdx.x, b = blockIdx.x;
    int base = b * 2048 + t * 8;
    int v[8];
    int tot = 0;
#pragma unroll
    for (int j = 0; j < 8; ++j) {
        int i = base + j;
        int c = (i < N_NODES) ? cnt[i] : 0;
        v[j] = tot;
        tot += c;
    }
    sd[t] = tot;
    __syncthreads();
    for (int off = 1; off < 256; off <<= 1) {
        int x = (t >= off) ? sd[t - off] : 0;
        __syncthreads();
        sd[t] += x;
        __syncthreads();
    }
    int excl = sd[t] - tot;
#pragma unroll
    for (int j = 0; j < 8; ++j) {
        int i = base + j;
        if (i < N_NODES) row_ptr[i] = excl + v[j];
    }
    if (t == 255) bsum[b] = sd[255];
}

// finalize row_ptr (adding serial prefix of <=25 block sums), init cursor, compute dinv
#define NB1 25
__global__ void k_scan3(const int* __restrict__ bsum, const int* __restrict__ cnt,
                        int* __restrict__ row_ptr, int* __restrict__ cursor,
                        float* __restrict__ dinv) {
    int i = blockIdx.x * blockDim.x + threadIdx.x;
    if (i < N_NODES) {
        int nb = i >> 11;
        int add = 0;
        for (int j = 0; j < nb; ++j) add += bsum[j];
        int v = row_ptr[i] + add;
        row_ptr[i] = v;
        cursor[i] = v;
        dinv[i] = rsqrtf((float)cnt[i] + 1.0f);
    }
    if (i == 0) row_ptr[N_NODES] = N_EDGES;
}

__global__ void k_scatter(const int* __restrict__ src, const int* __restrict__ dst,
                          const float* __restrict__ dinv, int* __restrict__ cursor,
                          int* __restrict__ csr_src, float* __restrict__ csr_w) {
    int e = blockIdx.x * blockDim.x + threadIdx.x;
    if (e < N_EDGES) {
        int s = src[e], d = dst[e];
        int pos = atomicAdd(&cursor[d], 1);
        csr_src[pos] = s;
        csr_w[pos] = dinv[s] * dinv[d];
    }
}

// -------------------- weight transpose + bf16 cast (all 3 layers, one launch) --------------------

__global__ __launch_bounds__(256) void k_wt3(const float* __restrict__ W0,
                                             const float* __restrict__ W1,
                                             const float* __restrict__ W2,
                                             ushort* __restrict__ Wt) {
    int l = blockIdx.x >> 4;
    const float* W = (l == 0) ? W0 : (l == 1) ? W1 : W2;
    ushort* o = Wt + (size_t)l * DIM * DIM;
    int t = threadIdx.x;
    int kbase = (blockIdx.x & 15) * 16;
    for (int kk = 0; kk < 16; ++kk) {
        int k = kbase + kk;
        o[(size_t)t * DIM + k] = f2bf(W[(size_t)k * DIM + t]);
    }
}

// -------------------- fp32 -> bf16 convert --------------------

__global__ __launch_bounds__(256) void k_xcvt(const float* __restrict__ x, ushort* __restrict__ o) {
    int i = blockIdx.x * blockDim.x + threadIdx.x;
    const size_t total4 = (size_t)N_NODES * DIM / 4;
    if ((size_t)i < total4) {
        float4 v = *(const float4*)(x + (size_t)i * 4);
        ushort4 u;
        u.x = f2bf(v.x); u.y = f2bf(v.y); u.z = f2bf(v.z); u.w = f2bf(v.w);
        *(ushort4*)(o + (size_t)i * 4) = u;
    }
}

// -------------------- bf16 MFMA GEMM: H[M x 256] = A[M x 256] @ W[256 x 256] --------------------
// Tile 128x256 (full width), BK=32, 4 waves, linear LDS + global_load_lds width-16.

#define GBM 128
#define GBK 32

__global__ __launch_bounds__(256) void k_gemm(const ushort* __restrict__ A,
                                              const ushort* __restrict__ Wt,
                                              ushort* __restrict__ H, int M) {
    __shared__ ushort As[GBM * GBK];        // 8 KB
    __shared__ ushort Bs[DIM * GBK];        // 16 KB
    int t = threadIdx.x;
    int lane = t & 63;
    int w = t >> 6;
    int wm = w >> 1, wn = w & 1;
    int bm0 = blockIdx.x * GBM;

    f32x4 acc[4][8];
#pragma unroll
    for (int m = 0; m < 4; ++m)
#pragma unroll
        for (int n = 0; n < 8; ++n) acc[m][n] = (f32x4)0.0f;

    int fr = lane & 15;
    int fq = lane >> 4;
    int lr = lane >> 2;
    int lc = (lane & 3) * 8;

    for (int k0 = 0; k0 < DIM; k0 += GBK) {
#pragma unroll
        for (int p = 0; p < 2; ++p) {
            int rb = (w + p * 4) * 16;
            int ga = bm0 + rb + lr;
            if (ga > M - 1) ga = M - 1;
            async16(A + (size_t)ga * DIM + k0 + lc, &As[rb * GBK]);
        }
#pragma unroll
        for (int p = 0; p < 4; ++p) {
            int rb = (w * 4 + p) * 16;
            async16(Wt + (size_t)(rb + lr) * DIM + k0 + lc, &Bs[rb * GBK]);
        }
        __syncthreads();
        bf16x8 af[4], bfv[8];
#pragma unroll
        for (int m = 0; m < 4; ++m)
            af[m] = *(const bf16x8*)&As[(wm * 64 + m * 16 + fr) * GBK + fq * 8];
#pragma unroll
        for (int n = 0; n < 8; ++n)
            bfv[n] = *(const bf16x8*)&Bs[(wn * 128 + n * 16 + fr) * GBK + fq * 8];
#pragma unroll
        for (int m = 0; m < 4; ++m)
#pragma unroll
            for (int n = 0; n < 8; ++n)
                acc[m][n] = __builtin_amdgcn_mfma_f32_16x16x32_bf16(af[m], bfv[n], acc[m][n], 0, 0, 0);
        __syncthreads();
    }
    // D row = (lane>>4)*4 + j, col = lane&15  [m89-verified]
#pragma unroll
    for (int m = 0; m < 4; ++m) {
        int row0 = bm0 + wm * 64 + m * 16 + fq * 4;
#pragma unroll
        for (int n = 0; n < 8; ++n) {
            int col = wn * 128 + n * 16 + fr;
#pragma unroll
            for (int j = 0; j < 4; ++j) {
                int row = row0 + j;
                if (row < M) H[(size_t)row * DIM + col] = f2bf(acc[m][n][j]);
            }
        }
    }
}

// -------------------- aggregation + bias + LayerNorm + ReLU (bf16 in/out) --------------------
// 4 nodes/block, 1 wave/node. Paired gather: lanes 0-31 fetch edge e's full row
// (ushort8 = 16B/lane), lanes 32-63 fetch edge e+1's row. 2 vmem per 4 edges.

__global__ __launch_bounds__(256) void k_agg_ln(const ushort* __restrict__ h,
                                                const int* __restrict__ rp,
                                                const int* __restrict__ cs,
                                                const float* __restrict__ cw,
                                                const float* __restrict__ dinv,
                                                const float* __restrict__ bias,
                                                const float* __restrict__ gamma,
                                                const float* __restrict__ beta,
                                                ushort* __restrict__ out) {
    int node = (blockIdx.x << 2) + (threadIdx.x >> 6);
    int lane = threadIdx.x & 63;
    int half = lane >> 5;
    int c0 = (lane & 31) << 3;   // 8 cols per lane, 32 lanes cover the row

    float a0[8], a1[8];
#pragma unroll
    for (int j = 0; j < 8; ++j) { a0[j] = 0.f; a1[j] = 0.f; }

    // self-loop term (lower half only; upper half would double it)
    float di = dinv[node];
    if (half == 0) {
        float sw = di * di;
        ushort8 sv = *(const ushort8*)(h + (size_t)node * DIM + c0);
#pragma unroll
        for (int j = 0; j < 8; ++j) a0[j] = sw * bf2f(sv[j]);
    }

    int e0 = rp[node], e1 = rp[node + 1];
    for (int e = e0; e < e1; e += 4) {
        int s0 = cs[e];
        float w0 = cw[e];
        int s1 = 0, s2 = 0, s3 = 0;
        float w1 = 0.f, w2 = 0.f, w3 = 0.f;
        if (e + 1 < e1) { s1 = cs[e + 1]; w1 = cw[e + 1]; }
        if (e + 2 < e1) { s2 = cs[e + 2]; w2 = cw[e + 2]; }
        if (e + 3 < e1) { s3 = cs[e + 3]; w3 = cw[e + 3]; }
        int   sa = half ? s1 : s0;
        float wa = half ? w1 : w0;
        int   sb = half ? s3 : s2;
        float wb = half ? w3 : w2;
        ushort8 va = *(const ushort8*)(h + (size_t)sa * DIM + c0);
        ushort8 vb = *(const ushort8*)(h + (size_t)sb * DIM + c0);
#pragma unroll
        for (int j = 0; j < 8; ++j) a0[j] += wa * bf2f(va[j]);
#pragma unroll
        for (int j = 0; j < 8; ++j) a1[j] += wb * bf2f(vb[j]);
    }

    float v[8];
#pragma unroll
    for (int j = 0; j < 8; ++j) v[j] = a0[j] + a1[j];
    // combine the two halves (each covered a disjoint edge subset of all 256 cols)
#pragma unroll
    for (int j = 0; j < 8; ++j) v[j] += __shfl_xor(v[j], 32);

    float4 b0 = *(const float4*)(bias + c0);
    float4 b1 = *(const float4*)(bias + c0 + 4);
    v[0] += b0.x; v[1] += b0.y; v[2] += b0.z; v[3] += b0.w;
    v[4] += b1.x; v[5] += b1.y; v[6] += b1.z; v[7] += b1.w;

    // LayerNorm: each 32-lane group holds all 256 cols exactly once
    float s1v = 0.f, s2v = 0.f;
#pragma unroll
    for (int j = 0; j < 8; ++j) { s1v += v[j]; s2v += v[j] * v[j]; }
#pragma unroll
    for (int off = 1; off < 32; off <<= 1) {
        s1v += __shfl_xor(s1v, off);
        s2v += __shfl_xor(s2v, off);
    }
    float mu = s1v * (1.0f / DIM);
    float var = s2v * (1.0f / DIM) - mu * mu;
    float rstd = rsqrtf(var + LN_EPS);

    float4 g0 = *(const float4*)(gamma + c0);
    float4 g1 = *(const float4*)(gamma + c0 + 4);
    float4 t0 = *(const float4*)(beta + c0);
    float4 t1 = *(const float4*)(beta + c0 + 4);
    float gg[8] = {g0.x, g0.y, g0.z, g0.w, g1.x, g1.y, g1.z, g1.w};
    float bb[8] = {t0.x, t0.y, t0.z, t0.w, t1.x, t1.y, t1.z, t1.w};
    if (half == 0) {
        ushort8 o;
#pragma unroll
        for (int j = 0; j < 8; ++j)
            o[j] = f2bf(fmaxf((v[j] - mu) * rstd * gg[j] + bb[j], 0.f));
        *(ushort8*)(out + (size_t)node * DIM + c0) = o;
    }
}

// -------------------- fused tail: pool (mean over graph) + FC + ReLU --------------------
// one block per graph; graph bounds via binary search on sorted batch

__global__ __launch_bounds__(256) void k_tail(const ushort* __restrict__ x,
                                              const int* __restrict__ batch,
                                              const float* __restrict__ fcw,
                                              const float* __restrict__ fcb,
                                              float* __restrict__ out) {
    __shared__ float pl[DIM];
    __shared__ int bounds[2];
    int g = blockIdx.x;
    int t = threadIdx.x;
    if (t < 2) {
        int target = g + t;
        int lo = 0, hi = N_NODES;
        while (lo < hi) {
            int mid = (lo + hi) >> 1;
            if (batch[mid] < target) lo = mid + 1; else hi = mid;
        }
        bounds[t] = lo;
    }
    __syncthreads();
    int r0 = bounds[0], r1 = bounds[1];

    float s0 = 0.f, s1 = 0.f, s2 = 0.f, s3 = 0.f;
    int r = r0;
    for (; r + 3 < r1; r += 4) {
        s0 += bf2f(x[(size_t)(r + 0) * DIM + t]);
        s1 += bf2f(x[(size_t)(r + 1) * DIM + t]);
        s2 += bf2f(x[(size_t)(r + 2) * DIM + t]);
        s3 += bf2f(x[(size_t)(r + 3) * DIM + t]);
    }
    for (; r < r1; ++r) s0 += bf2f(x[(size_t)r * DIM + t]);
    float s = (s0 + s1) + (s2 + s3);
    pl[t] = s / fmaxf((float)(r1 - r0), 1.0f);
    __syncthreads();

    float acc = fcb[t];
    const float* wrow = fcw + (size_t)t * DIM;
    for (int k = 0; k < DIM; k += 4) {
        float4 w4 = *(const float4*)(wrow + k);
        acc += pl[k] * w4.x + pl[k + 1] * w4.y + pl[k + 2] * w4.z + pl[k + 3] * w4.w;
    }
    out[(size_t)g * DIM + t] = fmaxf(acc, 0.0f);
}

// -------------------- launch --------------------

extern "C" void kernel_launch(void* const* d_in, const int* in_sizes, int n_in,
                              void* d_out, int out_size, void* d_ws, size_t ws_size,
                              hipStream_t stream) {
    const float* x = (const float*)d_in[0];
    const int* ei = (const int*)d_in[1];
    const int* src = ei;
    const int* dst = ei + N_EDGES;
    const int* batch = (const int*)d_in[2];
    const float* W[3] = {(const float*)d_in[3], (const float*)d_in[7], (const float*)d_in[11]};
    const float* bs[3] = {(const float*)d_in[4], (const float*)d_in[8], (const float*)d_in[12]};
    const float* gs[3] = {(const float*)d_in[5], (const float*)d_in[9], (const float*)d_in[13]};
    const float* be[3] = {(const float*)d_in[6], (const float*)d_in[10], (const float*)d_in[14]};
    const float* fcw = (const float*)d_in[15];
    const float* fcb = (const float*)d_in[16];
    float* out = (float*)d_out;

    char* p = (char*)d_ws;
    auto alloc = [&](size_t bytes) {
        char* r = p;
        p += (bytes + 255) & ~(size_t)255;
        return r;
    };
    ushort* h       = (ushort*)alloc((size_t)N_NODES * DIM * 2);
    ushort* bufA    = (ushort*)alloc((size_t)N_NODES * DIM * 2);
    ushort* bufB    = (ushort*)alloc((size_t)N_NODES * DIM * 2);
    ushort* Wt      = (ushort*)alloc((size_t)3 * DIM * DIM * 2);
    int*   cnt     = (int*)alloc((size_t)N_NODES * 4);
    int*   row_ptr = (int*)alloc((size_t)(N_NODES + 1) * 4);
    int*   cursor  = (int*)alloc((size_t)N_NODES * 4);
    float* dinv    = (float*)alloc((size_t)N_NODES * 4);
    int*   csr_src = (int*)alloc((size_t)N_EDGES * 4);
    float* csr_w   = (float*)alloc((size_t)N_EDGES * 4);
    int*   bsum    = (int*)alloc(256 * 4);

    hipMemsetAsync(cnt, 0, (size_t)N_NODES * 4, stream);

    const int TPB = 256;
    int gridE = (N_EDGES + TPB - 1) / TPB;
    int gridN = (N_NODES + TPB - 1) / TPB;

    k_wt3<<<48, TPB, 0, stream>>>(W[0], W[1], W[2], Wt);
    {
        int tot4 = N_NODES * DIM / 4;
        k_xcvt<<<(tot4 + TPB - 1) / TPB, TPB, 0, stream>>>(x, bufA);
    }

    k_hist<<<gridE, TPB, 0, stream>>>(dst, cnt);
    k_scan1<<<NB1, TPB, 0, stream>>>(cnt, row_ptr, bsum);
    k_scan3<<<gridN, TPB, 0, stream>>>(bsum, cnt, row_ptr, cursor, dinv);
    k_scatter<<<gridE, TPB, 0, stream>>>(src, dst, dinv, cursor, csr_src, csr_w);

    ushort* cur = bufA;
    ushort* nxt = bufB;
    for (int l = 0; l < 3; ++l) {
        int gg = (N_NODES + GBM - 1) / GBM;
        k_gemm<<<gg, TPB, 0, stream>>>(cur, Wt + (size_t)l * DIM * DIM, h, N_NODES);
        k_agg_ln<<<N_NODES / 4, TPB, 0, stream>>>(h, row_ptr, csr_src, csr_w, dinv,
                                                  bs[l], gs[l], be[l], nxt);
        ushort* tmp = cur; cur = nxt; nxt = tmp;
    }

    k_tail<<<N_GRAPHS, TPB, 0, stream>>>(cur, batch, fcw, fcb, out);
}

// Round 6
// 415.937 us; speedup vs baseline: 1.1994x; 1.0311x over previous
//
#include <hip/hip_runtime.h>
#include <hip/hip_bf16.h>

#define N_NODES 50000
#define N_EDGES 800000
#define N_GRAPHS 512
#define DIM 256
#define LN_EPS 1e-5f

typedef __attribute__((ext_vector_type(8))) short bf16x8;
typedef __attribute__((ext_vector_type(4))) float f32x4;
typedef __attribute__((ext_vector_type(8))) ushort ushort8;

__device__ __forceinline__ float bf2f(ushort u) {
    union { float f; unsigned int i; } c;
    c.i = ((unsigned int)u) << 16;
    return c.f;
}
__device__ __forceinline__ ushort f2bf(float f) {
    union { float f; unsigned int i; } c;
    c.f = f;
    unsigned int r = (c.i + 0x7fffu + ((c.i >> 16) & 1u)) >> 16;
    return (ushort)r;
}

// async global -> LDS, 16B per lane. lds base must be wave-uniform; HW adds lane*16.
__device__ __forceinline__ void async16(const ushort* g, ushort* l) {
    __builtin_amdgcn_global_load_lds(
        (const __attribute__((address_space(1))) unsigned int*)g,
        (__attribute__((address_space(3))) unsigned int*)l,
        16, 0, 0);
}

// -------------------- CSR build --------------------

__global__ void k_hist(const int* __restrict__ dst, int* __restrict__ cnt) {
    int e = blockIdx.x * blockDim.x + threadIdx.x;
    const int HE = N_EDGES / 2;
    if (e < HE) {
        int d0 = dst[e];
        int d1 = dst[e + HE];
        atomicAdd(&cnt[d0], 1);
        atomicAdd(&cnt[d1], 1);
    }
}

__global__ __launch_bounds__(256) void k_scan1(const int* __restrict__ cnt,
                                               int* __restrict__ row_ptr,
                                               int* __restrict__ bsum) {
    __shared__ int sd[256];
    int t = threadIdx.x, b = blockIdx.x;
    int base = b * 2048 + t * 8;
    int v[8];
    int tot = 0;
#pragma unroll
    for (int j = 0; j < 8; ++j) {
        int i = base + j;
        int c = (i < N_NODES) ? cnt[i] : 0;
        v[j] = tot;
        tot += c;
    }
    sd[t] = tot;
    __syncthreads();
    for (int off = 1; off < 256; off <<= 1) {
        int x = (t >= off) ? sd[t - off] : 0;
        __syncthreads();
        sd[t] += x;
        __syncthreads();
    }
    int excl = sd[t] - tot;
#pragma unroll
    for (int j = 0; j < 8; ++j) {
        int i = base + j;
        if (i < N_NODES) row_ptr[i] = excl + v[j];
    }
    if (t == 255) bsum[b] = sd[255];
}

// finalize row_ptr (adding serial prefix of <=25 block sums), init cursor, compute dinv
#define NB1 25
__global__ void k_scan3(const int* __restrict__ bsum, const int* __restrict__ cnt,
                        int* __restrict__ row_ptr, int* __restrict__ cursor,
                        float* __restrict__ dinv) {
    int i = blockIdx.x * blockDim.x + threadIdx.x;
    if (i < N_NODES) {
        int nb = i >> 11;
        int add = 0;
        for (int j = 0; j < nb; ++j) add += bsum[j];
        int v = row_ptr[i] + add;
        row_ptr[i] = v;
        cursor[i] = v;
        dinv[i] = rsqrtf((float)cnt[i] + 1.0f);
    }
    if (i == 0) row_ptr[N_NODES] = N_EDGES;
}

// packed CSR entry: .x = src node, .y = bit-cast weight. One 8B write per edge.
__global__ void k_scatter(const int* __restrict__ src, const int* __restrict__ dst,
                          const float* __restrict__ dinv, int* __restrict__ cursor,
                          int2* __restrict__ csr) {
    int e = blockIdx.x * blockDim.x + threadIdx.x;
    const int HE = N_EDGES / 2;
    if (e < HE) {
        int s0 = src[e],      d0 = dst[e];
        int s1 = src[e + HE], d1 = dst[e + HE];
        float w0 = dinv[s0] * dinv[d0];
        float w1 = dinv[s1] * dinv[d1];
        int p0 = atomicAdd(&cursor[d0], 1);
        int p1 = atomicAdd(&cursor[d1], 1);
        csr[p0] = make_int2(s0, __float_as_int(w0));
        csr[p1] = make_int2(s1, __float_as_int(w1));
    }
}

// -------------------- weight transpose + bf16 cast (all 3 layers, one launch) --------------------

__global__ __launch_bounds__(256) void k_wt3(const float* __restrict__ W0,
                                             const float* __restrict__ W1,
                                             const float* __restrict__ W2,
                                             ushort* __restrict__ Wt) {
    int l = blockIdx.x >> 4;
    const float* W = (l == 0) ? W0 : (l == 1) ? W1 : W2;
    ushort* o = Wt + (size_t)l * DIM * DIM;
    int t = threadIdx.x;
    int kbase = (blockIdx.x & 15) * 16;
    for (int kk = 0; kk < 16; ++kk) {
        int k = kbase + kk;
        o[(size_t)t * DIM + k] = f2bf(W[(size_t)k * DIM + t]);
    }
}

// -------------------- fp32 -> bf16 convert --------------------

__global__ __launch_bounds__(256) void k_xcvt(const float* __restrict__ x, ushort* __restrict__ o) {
    int i = blockIdx.x * blockDim.x + threadIdx.x;
    const size_t total4 = (size_t)N_NODES * DIM / 4;
    if ((size_t)i < total4) {
        float4 v = *(const float4*)(x + (size_t)i * 4);
        ushort4 u;
        u.x = f2bf(v.x); u.y = f2bf(v.y); u.z = f2bf(v.z); u.w = f2bf(v.w);
        *(ushort4*)(o + (size_t)i * 4) = u;
    }
}

// -------------------- bf16 MFMA GEMM: H[M x 256] = A[M x 256] @ W[256 x 256] --------------------
// Tile 128x256 (full width), BK=32, 4 waves, linear LDS + global_load_lds width-16.

#define GBM 128
#define GBK 32

__global__ __launch_bounds__(256) void k_gemm(const ushort* __restrict__ A,
                                              const ushort* __restrict__ Wt,
                                              ushort* __restrict__ H, int M) {
    __shared__ ushort As[GBM * GBK];        // 8 KB
    __shared__ ushort Bs[DIM * GBK];        // 16 KB
    int t = threadIdx.x;
    int lane = t & 63;
    int w = t >> 6;
    int wm = w >> 1, wn = w & 1;
    int bm0 = blockIdx.x * GBM;

    f32x4 acc[4][8];
#pragma unroll
    for (int m = 0; m < 4; ++m)
#pragma unroll
        for (int n = 0; n < 8; ++n) acc[m][n] = (f32x4)0.0f;

    int fr = lane & 15;
    int fq = lane >> 4;
    int lr = lane >> 2;
    int lc = (lane & 3) * 8;

    for (int k0 = 0; k0 < DIM; k0 += GBK) {
#pragma unroll
        for (int p = 0; p < 2; ++p) {
            int rb = (w + p * 4) * 16;
            int ga = bm0 + rb + lr;
            if (ga > M - 1) ga = M - 1;
            async16(A + (size_t)ga * DIM + k0 + lc, &As[rb * GBK]);
        }
#pragma unroll
        for (int p = 0; p < 4; ++p) {
            int rb = (w * 4 + p) * 16;
            async16(Wt + (size_t)(rb + lr) * DIM + k0 + lc, &Bs[rb * GBK]);
        }
        __syncthreads();
        bf16x8 af[4], bfv[8];
#pragma unroll
        for (int m = 0; m < 4; ++m)
            af[m] = *(const bf16x8*)&As[(wm * 64 + m * 16 + fr) * GBK + fq * 8];
#pragma unroll
        for (int n = 0; n < 8; ++n)
            bfv[n] = *(const bf16x8*)&Bs[(wn * 128 + n * 16 + fr) * GBK + fq * 8];
#pragma unroll
        for (int m = 0; m < 4; ++m)
#pragma unroll
            for (int n = 0; n < 8; ++n)
                acc[m][n] = __builtin_amdgcn_mfma_f32_16x16x32_bf16(af[m], bfv[n], acc[m][n], 0, 0, 0);
        __syncthreads();
    }
    // D row = (lane>>4)*4 + j, col = lane&15  [m89-verified]
#pragma unroll
    for (int m = 0; m < 4; ++m) {
        int row0 = bm0 + wm * 64 + m * 16 + fq * 4;
#pragma unroll
        for (int n = 0; n < 8; ++n) {
            int col = wn * 128 + n * 16 + fr;
#pragma unroll
            for (int j = 0; j < 4; ++j) {
                int row = row0 + j;
                if (row < M) H[(size_t)row * DIM + col] = f2bf(acc[m][n][j]);
            }
        }
    }
}

// -------------------- aggregation + bias + LayerNorm + ReLU (bf16 in/out) --------------------
// 4 nodes/block, 1 wave/node, wave split in two 32-lane halves each gathering a
// full 512B row (ushort8/lane). Edge metadata loaded coalesced (64 edges/int2
// batch into registers) and broadcast per-edge via __shfl — ~1 vmem instr/edge.

__global__ __launch_bounds__(256) void k_agg_ln(const ushort* __restrict__ h,
                                                const int* __restrict__ rp,
                                                const int2* __restrict__ csr,
                                                const float* __restrict__ dinv,
                                                const float* __restrict__ bias,
                                                const float* __restrict__ gamma,
                                                const float* __restrict__ beta,
                                                ushort* __restrict__ out) {
    int node = (blockIdx.x << 2) + (threadIdx.x >> 6);
    int lane = threadIdx.x & 63;
    int half = lane >> 5;
    int c0 = (lane & 31) << 3;   // 8 cols per lane, 32 lanes cover the row

    float a0[8], a1[8];
#pragma unroll
    for (int j = 0; j < 8; ++j) { a0[j] = 0.f; a1[j] = 0.f; }

    // self-loop term (lower half only)
    float di = dinv[node];
    if (half == 0) {
        float sw = di * di;
        ushort8 sv = *(const ushort8*)(h + (size_t)node * DIM + c0);
#pragma unroll
        for (int j = 0; j < 8; ++j) a0[j] = sw * bf2f(sv[j]);
    }

    int e0 = rp[node], e1 = rp[node + 1];
    for (int eb = e0; eb < e1; eb += 64) {
        int idx = eb + lane;
        if (idx > N_EDGES - 1) idx = N_EDGES - 1;
        int2 md = csr[idx];               // lane L holds edge eb+L
        int n = e1 - eb;
        if (n > 64) n = 64;
        // this half processes edges jj = half, half+2, ... < n (pairwise unrolled)
        int jj = half;
        for (; jj + 2 < n; jj += 4) {
            int s0 = __shfl(md.x, jj);
            float w0 = __int_as_float(__shfl(md.y, jj));
            int s1 = __shfl(md.x, jj + 2);
            float w1 = __int_as_float(__shfl(md.y, jj + 2));
            ushort8 v0 = *(const ushort8*)(h + (size_t)s0 * DIM + c0);
            ushort8 v1 = *(const ushort8*)(h + (size_t)s1 * DIM + c0);
#pragma unroll
            for (int j = 0; j < 8; ++j) a0[j] += w0 * bf2f(v0[j]);
#pragma unroll
            for (int j = 0; j < 8; ++j) a1[j] += w1 * bf2f(v1[j]);
        }
        if (jj < n) {
            int s = __shfl(md.x, jj);
            float w = __int_as_float(__shfl(md.y, jj));
            ushort8 v = *(const ushort8*)(h + (size_t)s * DIM + c0);
#pragma unroll
            for (int j = 0; j < 8; ++j) a0[j] += w * bf2f(v[j]);
        }
    }

    float v[8];
#pragma unroll
    for (int j = 0; j < 8; ++j) v[j] = a0[j] + a1[j];
    // combine the two halves (disjoint edge subsets, same 256 cols)
#pragma unroll
    for (int j = 0; j < 8; ++j) v[j] += __shfl_xor(v[j], 32);

    float4 b0 = *(const float4*)(bias + c0);
    float4 b1 = *(const float4*)(bias + c0 + 4);
    v[0] += b0.x; v[1] += b0.y; v[2] += b0.z; v[3] += b0.w;
    v[4] += b1.x; v[5] += b1.y; v[6] += b1.z; v[7] += b1.w;

    // LayerNorm: each 32-lane group holds all 256 cols exactly once
    float s1v = 0.f, s2v = 0.f;
#pragma unroll
    for (int j = 0; j < 8; ++j) { s1v += v[j]; s2v += v[j] * v[j]; }
#pragma unroll
    for (int off = 1; off < 32; off <<= 1) {
        s1v += __shfl_xor(s1v, off);
        s2v += __shfl_xor(s2v, off);
    }
    float mu = s1v * (1.0f / DIM);
    float var = s2v * (1.0f / DIM) - mu * mu;
    float rstd = rsqrtf(var + LN_EPS);

    float4 g0 = *(const float4*)(gamma + c0);
    float4 g1 = *(const float4*)(gamma + c0 + 4);
    float4 t0 = *(const float4*)(beta + c0);
    float4 t1 = *(const float4*)(beta + c0 + 4);
    float gg[8] = {g0.x, g0.y, g0.z, g0.w, g1.x, g1.y, g1.z, g1.w};
    float bb[8] = {t0.x, t0.y, t0.z, t0.w, t1.x, t1.y, t1.z, t1.w};
    if (half == 0) {
        ushort8 o;
#pragma unroll
        for (int j = 0; j < 8; ++j)
            o[j] = f2bf(fmaxf((v[j] - mu) * rstd * gg[j] + bb[j], 0.f));
        *(ushort8*)(out + (size_t)node * DIM + c0) = o;
    }
}

// -------------------- fused tail: pool (mean over graph) + FC + ReLU --------------------

__global__ __launch_bounds__(256) void k_tail(const ushort* __restrict__ x,
                                              const int* __restrict__ batch,
                                              const float* __restrict__ fcw,
                                              const float* __restrict__ fcb,
                                              float* __restrict__ out) {
    __shared__ float pl[DIM];
    __shared__ int bounds[2];
    int g = blockIdx.x;
    int t = threadIdx.x;
    if (t < 2) {
        int target = g + t;
        int lo = 0, hi = N_NODES;
        while (lo < hi) {
            int mid = (lo + hi) >> 1;
            if (batch[mid] < target) lo = mid + 1; else hi = mid;
        }
        bounds[t] = lo;
    }
    __syncthreads();
    int r0 = bounds[0], r1 = bounds[1];

    float s0 = 0.f, s1 = 0.f, s2 = 0.f, s3 = 0.f;
    int r = r0;
    for (; r + 3 < r1; r += 4) {
        s0 += bf2f(x[(size_t)(r + 0) * DIM + t]);
        s1 += bf2f(x[(size_t)(r + 1) * DIM + t]);
        s2 += bf2f(x[(size_t)(r + 2) * DIM + t]);
        s3 += bf2f(x[(size_t)(r + 3) * DIM + t]);
    }
    for (; r < r1; ++r) s0 += bf2f(x[(size_t)r * DIM + t]);
    float s = (s0 + s1) + (s2 + s3);
    pl[t] = s / fmaxf((float)(r1 - r0), 1.0f);
    __syncthreads();

    float acc = fcb[t];
    const float* wrow = fcw + (size_t)t * DIM;
    for (int k = 0; k < DIM; k += 4) {
        float4 w4 = *(const float4*)(wrow + k);
        acc += pl[k] * w4.x + pl[k + 1] * w4.y + pl[k + 2] * w4.z + pl[k + 3] * w4.w;
    }
    out[(size_t)g * DIM + t] = fmaxf(acc, 0.0f);
}

// -------------------- launch --------------------

extern "C" void kernel_launch(void* const* d_in, const int* in_sizes, int n_in,
                              void* d_out, int out_size, void* d_ws, size_t ws_size,
                              hipStream_t stream) {
    const float* x = (const float*)d_in[0];
    const int* ei = (const int*)d_in[1];
    const int* src = ei;
    const int* dst = ei + N_EDGES;
    const int* batch = (const int*)d_in[2];
    const float* W[3] = {(const float*)d_in[3], (const float*)d_in[7], (const float*)d_in[11]};
    const float* bs[3] = {(const float*)d_in[4], (const float*)d_in[8], (const float*)d_in[12]};
    const float* gs[3] = {(const float*)d_in[5], (const float*)d_in[9], (const float*)d_in[13]};
    const float* be[3] = {(const float*)d_in[6], (const float*)d_in[10], (const float*)d_in[14]};
    const float* fcw = (const float*)d_in[15];
    const float* fcb = (const float*)d_in[16];
    float* out = (float*)d_out;

    char* p = (char*)d_ws;
    auto alloc = [&](size_t bytes) {
        char* r = p;
        p += (bytes + 255) & ~(size_t)255;
        return r;
    };
    ushort* h       = (ushort*)alloc((size_t)N_NODES * DIM * 2);
    ushort* bufA    = (ushort*)alloc((size_t)N_NODES * DIM * 2);
    ushort* bufB    = (ushort*)alloc((size_t)N_NODES * DIM * 2);
    ushort* Wt      = (ushort*)alloc((size_t)3 * DIM * DIM * 2);
    int*   cnt     = (int*)alloc((size_t)N_NODES * 4);
    int*   row_ptr = (int*)alloc((size_t)(N_NODES + 1) * 4);
    int*   cursor  = (int*)alloc((size_t)N_NODES * 4);
    float* dinv    = (float*)alloc((size_t)N_NODES * 4);
    int2*  csr     = (int2*)alloc((size_t)N_EDGES * 8);
    int*   bsum    = (int*)alloc(256 * 4);

    hipMemsetAsync(cnt, 0, (size_t)N_NODES * 4, stream);

    const int TPB = 256;
    int gridN = (N_NODES + TPB - 1) / TPB;
    int gridE2 = (N_EDGES / 2 + TPB - 1) / TPB;

    k_wt3<<<48, TPB, 0, stream>>>(W[0], W[1], W[2], Wt);
    {
        int tot4 = N_NODES * DIM / 4;
        k_xcvt<<<(tot4 + TPB - 1) / TPB, TPB, 0, stream>>>(x, bufA);
    }

    k_hist<<<gridE2, TPB, 0, stream>>>(dst, cnt);
    k_scan1<<<NB1, TPB, 0, stream>>>(cnt, row_ptr, bsum);
    k_scan3<<<gridN, TPB, 0, stream>>>(bsum, cnt, row_ptr, cursor, dinv);
    k_scatter<<<gridE2, TPB, 0, stream>>>(src, dst, dinv, cursor, csr);

    ushort* cur = bufA;
    ushort* nxt = bufB;
    for (int l = 0; l < 3; ++l) {
        int gg = (N_NODES + GBM - 1) / GBM;
        k_gemm<<<gg, TPB, 0, stream>>>(cur, Wt + (size_t)l * DIM * DIM, h, N_NODES);
        k_agg_ln<<<N_NODES / 4, TPB, 0, stream>>>(h, row_ptr, csr, dinv,
                                                  bs[l], gs[l], be[l], nxt);
        ushort* tmp = cur; cur = nxt; nxt = tmp;
    }

    k_tail<<<N_GRAPHS, TPB, 0, stream>>>(cur, batch, fcw, fcb, out);
}

// Round 7
// 415.551 us; speedup vs baseline: 1.2005x; 1.0009x over previous
//
#include <hip/hip_runtime.h>
#include <hip/hip_bf16.h>

#define N_NODES 50000
#define N_EDGES 800000
#define N_GRAPHS 512
#define DIM 256
#define LN_EPS 1e-5f

typedef __attribute__((ext_vector_type(8))) short bf16x8;
typedef __attribute__((ext_vector_type(4))) float f32x4;
typedef __attribute__((ext_vector_type(8))) ushort ushort8;

__device__ __forceinline__ float bf2f(ushort u) {
    union { float f; unsigned int i; } c;
    c.i = ((unsigned int)u) << 16;
    return c.f;
}
__device__ __forceinline__ ushort f2bf(float f) {
    union { float f; unsigned int i; } c;
    c.f = f;
    unsigned int r = (c.i + 0x7fffu + ((c.i >> 16) & 1u)) >> 16;
    return (ushort)r;
}

// async global -> LDS, 16B per lane. lds base must be wave-uniform; HW adds lane*16.
__device__ __forceinline__ void async16(const ushort* g, ushort* l) {
    __builtin_amdgcn_global_load_lds(
        (const __attribute__((address_space(1))) unsigned int*)g,
        (__attribute__((address_space(3))) unsigned int*)l,
        16, 0, 0);
}

// -------------------- CSR build --------------------

__global__ void k_hist(const int* __restrict__ dst, int* __restrict__ cnt) {
    int e = blockIdx.x * blockDim.x + threadIdx.x;
    const int QE = N_EDGES / 4;
    if (e < QE) {
        int d0 = dst[e];
        int d1 = dst[e + QE];
        int d2 = dst[e + 2 * QE];
        int d3 = dst[e + 3 * QE];
        atomicAdd(&cnt[d0], 1);
        atomicAdd(&cnt[d1], 1);
        atomicAdd(&cnt[d2], 1);
        atomicAdd(&cnt[d3], 1);
    }
}

__global__ __launch_bounds__(256) void k_scan1(const int* __restrict__ cnt,
                                               int* __restrict__ row_ptr,
                                               int* __restrict__ bsum) {
    __shared__ int sd[256];
    int t = threadIdx.x, b = blockIdx.x;
    int base = b * 2048 + t * 8;
    int v[8];
    int tot = 0;
#pragma unroll
    for (int j = 0; j < 8; ++j) {
        int i = base + j;
        int c = (i < N_NODES) ? cnt[i] : 0;
        v[j] = tot;
        tot += c;
    }
    sd[t] = tot;
    __syncthreads();
    for (int off = 1; off < 256; off <<= 1) {
        int x = (t >= off) ? sd[t - off] : 0;
        __syncthreads();
        sd[t] += x;
        __syncthreads();
    }
    int excl = sd[t] - tot;
#pragma unroll
    for (int j = 0; j < 8; ++j) {
        int i = base + j;
        if (i < N_NODES) row_ptr[i] = excl + v[j];
    }
    if (t == 255) bsum[b] = sd[255];
}

// finalize row_ptr (adding serial prefix of <=25 block sums), init cursor, compute dinv
#define NB1 25
__global__ void k_scan3(const int* __restrict__ bsum, const int* __restrict__ cnt,
                        int* __restrict__ row_ptr, int* __restrict__ cursor,
                        float* __restrict__ dinv) {
    int i = blockIdx.x * blockDim.x + threadIdx.x;
    if (i < N_NODES) {
        int nb = i >> 11;
        int add = 0;
        for (int j = 0; j < nb; ++j) add += bsum[j];
        int v = row_ptr[i] + add;
        row_ptr[i] = v;
        cursor[i] = v;
        dinv[i] = rsqrtf((float)cnt[i] + 1.0f);
    }
    if (i == 0) row_ptr[N_NODES] = N_EDGES;
}

// packed CSR entry: .x = src node, .y = bit-cast weight. 4 independent chains/thread.
__global__ void k_scatter(const int* __restrict__ src, const int* __restrict__ dst,
                          const float* __restrict__ dinv, int* __restrict__ cursor,
                          int2* __restrict__ csr) {
    int e = blockIdx.x * blockDim.x + threadIdx.x;
    const int QE = N_EDGES / 4;
    if (e >= QE) return;
    int s0 = src[e],          d0 = dst[e];
    int s1 = src[e + QE],     d1 = dst[e + QE];
    int s2 = src[e + 2 * QE], d2 = dst[e + 2 * QE];
    int s3 = src[e + 3 * QE], d3 = dst[e + 3 * QE];
    float w0 = dinv[s0] * dinv[d0];
    float w1 = dinv[s1] * dinv[d1];
    float w2 = dinv[s2] * dinv[d2];
    float w3 = dinv[s3] * dinv[d3];
    int p0 = atomicAdd(&cursor[d0], 1);
    int p1 = atomicAdd(&cursor[d1], 1);
    int p2 = atomicAdd(&cursor[d2], 1);
    int p3 = atomicAdd(&cursor[d3], 1);
    csr[p0] = make_int2(s0, __float_as_int(w0));
    csr[p1] = make_int2(s1, __float_as_int(w1));
    csr[p2] = make_int2(s2, __float_as_int(w2));
    csr[p3] = make_int2(s3, __float_as_int(w3));
}

// -------------------- weight transpose + bf16 cast (all 3 layers, one launch) --------------------

__global__ __launch_bounds__(256) void k_wt3(const float* __restrict__ W0,
                                             const float* __restrict__ W1,
                                             const float* __restrict__ W2,
                                             ushort* __restrict__ Wt) {
    int l = blockIdx.x >> 4;
    const float* W = (l == 0) ? W0 : (l == 1) ? W1 : W2;
    ushort* o = Wt + (size_t)l * DIM * DIM;
    int t = threadIdx.x;
    int kbase = (blockIdx.x & 15) * 16;
    for (int kk = 0; kk < 16; ++kk) {
        int k = kbase + kk;
        o[(size_t)t * DIM + k] = f2bf(W[(size_t)k * DIM + t]);
    }
}

// -------------------- fp32 -> bf16 convert --------------------

__global__ __launch_bounds__(256) void k_xcvt(const float* __restrict__ x, ushort* __restrict__ o) {
    int i = blockIdx.x * blockDim.x + threadIdx.x;
    const size_t total4 = (size_t)N_NODES * DIM / 4;
    if ((size_t)i < total4) {
        float4 v = *(const float4*)(x + (size_t)i * 4);
        ushort4 u;
        u.x = f2bf(v.x); u.y = f2bf(v.y); u.z = f2bf(v.z); u.w = f2bf(v.w);
        *(ushort4*)(o + (size_t)i * 4) = u;
    }
}

// -------------------- bf16 MFMA GEMM: H[M x 256] = A[M x 256] @ W[256 x 256] --------------------
// Tile 128x256 (full width), BK=32, 4 waves, linear LDS + global_load_lds width-16.

#define GBM 128
#define GBK 32

__global__ __launch_bounds__(256) void k_gemm(const ushort* __restrict__ A,
                                              const ushort* __restrict__ Wt,
                                              ushort* __restrict__ H, int M) {
    __shared__ ushort As[GBM * GBK];        // 8 KB
    __shared__ ushort Bs[DIM * GBK];        // 16 KB
    int t = threadIdx.x;
    int lane = t & 63;
    int w = t >> 6;
    int wm = w >> 1, wn = w & 1;
    int bm0 = blockIdx.x * GBM;

    f32x4 acc[4][8];
#pragma unroll
    for (int m = 0; m < 4; ++m)
#pragma unroll
        for (int n = 0; n < 8; ++n) acc[m][n] = (f32x4)0.0f;

    int fr = lane & 15;
    int fq = lane >> 4;
    int lr = lane >> 2;
    int lc = (lane & 3) * 8;

    for (int k0 = 0; k0 < DIM; k0 += GBK) {
#pragma unroll
        for (int p = 0; p < 2; ++p) {
            int rb = (w + p * 4) * 16;
            int ga = bm0 + rb + lr;
            if (ga > M - 1) ga = M - 1;
            async16(A + (size_t)ga * DIM + k0 + lc, &As[rb * GBK]);
        }
#pragma unroll
        for (int p = 0; p < 4; ++p) {
            int rb = (w * 4 + p) * 16;
            async16(Wt + (size_t)(rb + lr) * DIM + k0 + lc, &Bs[rb * GBK]);
        }
        __syncthreads();
        bf16x8 af[4], bfv[8];
#pragma unroll
        for (int m = 0; m < 4; ++m)
            af[m] = *(const bf16x8*)&As[(wm * 64 + m * 16 + fr) * GBK + fq * 8];
#pragma unroll
        for (int n = 0; n < 8; ++n)
            bfv[n] = *(const bf16x8*)&Bs[(wn * 128 + n * 16 + fr) * GBK + fq * 8];
#pragma unroll
        for (int m = 0; m < 4; ++m)
#pragma unroll
            for (int n = 0; n < 8; ++n)
                acc[m][n] = __builtin_amdgcn_mfma_f32_16x16x32_bf16(af[m], bfv[n], acc[m][n], 0, 0, 0);
        __syncthreads();
    }
    // D row = (lane>>4)*4 + j, col = lane&15  [m89-verified]
#pragma unroll
    for (int m = 0; m < 4; ++m) {
        int row0 = bm0 + wm * 64 + m * 16 + fq * 4;
#pragma unroll
        for (int n = 0; n < 8; ++n) {
            int col = wn * 128 + n * 16 + fr;
#pragma unroll
            for (int j = 0; j < 4; ++j) {
                int row = row0 + j;
                if (row < M) H[(size_t)row * DIM + col] = f2bf(acc[m][n][j]);
            }
        }
    }
}

// -------------------- aggregation + bias + LayerNorm + ReLU (bf16 in/out) --------------------
// 4 nodes/block, 1 wave/node, two 32-lane halves each gathering full 512B rows
// (ushort8/lane). Metadata: coalesced int2 batch + __shfl broadcast. Quad-unrolled:
// 4 gathers in flight per half, 2 accumulators (VGPR < 64 to keep 8 waves/SIMD).

__global__ __launch_bounds__(256) void k_agg_ln(const ushort* __restrict__ h,
                                                const int* __restrict__ rp,
                                                const int2* __restrict__ csr,
                                                const float* __restrict__ dinv,
                                                const float* __restrict__ bias,
                                                const float* __restrict__ gamma,
                                                const float* __restrict__ beta,
                                                ushort* __restrict__ out) {
    int node = (blockIdx.x << 2) + (threadIdx.x >> 6);
    int lane = threadIdx.x & 63;
    int half = lane >> 5;
    int c0 = (lane & 31) << 3;   // 8 cols per lane, 32 lanes cover the row

    float a0[8], a1[8];
#pragma unroll
    for (int j = 0; j < 8; ++j) { a0[j] = 0.f; a1[j] = 0.f; }

    // self-loop term (lower half only)
    float di = dinv[node];
    if (half == 0) {
        float sw = di * di;
        ushort8 sv = *(const ushort8*)(h + (size_t)node * DIM + c0);
#pragma unroll
        for (int j = 0; j < 8; ++j) a0[j] = sw * bf2f(sv[j]);
    }

    int e0 = rp[node], e1 = rp[node + 1];
    for (int eb = e0; eb < e1; eb += 64) {
        int idx = eb + lane;
        if (idx > N_EDGES - 1) idx = N_EDGES - 1;
        int2 md = csr[idx];               // lane L holds edge eb+L
        int n = e1 - eb;
        if (n > 64) n = 64;
        // this half processes edges jj ≡ half (mod 2), quad-unrolled
        int jj = half;
        for (; jj + 6 < n; jj += 8) {
            int s0 = __shfl(md.x, jj);
            float w0 = __int_as_float(__shfl(md.y, jj));
            int s1 = __shfl(md.x, jj + 2);
            float w1 = __int_as_float(__shfl(md.y, jj + 2));
            int s2 = __shfl(md.x, jj + 4);
            float w2 = __int_as_float(__shfl(md.y, jj + 4));
            int s3 = __shfl(md.x, jj + 6);
            float w3 = __int_as_float(__shfl(md.y, jj + 6));
            ushort8 v0 = *(const ushort8*)(h + (size_t)s0 * DIM + c0);
            ushort8 v1 = *(const ushort8*)(h + (size_t)s1 * DIM + c0);
            ushort8 v2 = *(const ushort8*)(h + (size_t)s2 * DIM + c0);
            ushort8 v3 = *(const ushort8*)(h + (size_t)s3 * DIM + c0);
#pragma unroll
            for (int j = 0; j < 8; ++j) a0[j] += w0 * bf2f(v0[j]);
#pragma unroll
            for (int j = 0; j < 8; ++j) a1[j] += w1 * bf2f(v1[j]);
#pragma unroll
            for (int j = 0; j < 8; ++j) a0[j] += w2 * bf2f(v2[j]);
#pragma unroll
            for (int j = 0; j < 8; ++j) a1[j] += w3 * bf2f(v3[j]);
        }
        for (; jj + 2 < n; jj += 4) {
            int s0 = __shfl(md.x, jj);
            float w0 = __int_as_float(__shfl(md.y, jj));
            int s1 = __shfl(md.x, jj + 2);
            float w1 = __int_as_float(__shfl(md.y, jj + 2));
            ushort8 v0 = *(const ushort8*)(h + (size_t)s0 * DIM + c0);
            ushort8 v1 = *(const ushort8*)(h + (size_t)s1 * DIM + c0);
#pragma unroll
            for (int j = 0; j < 8; ++j) a0[j] += w0 * bf2f(v0[j]);
#pragma unroll
            for (int j = 0; j < 8; ++j) a1[j] += w1 * bf2f(v1[j]);
        }
        if (jj < n) {
            int s = __shfl(md.x, jj);
            float w = __int_as_float(__shfl(md.y, jj));
            ushort8 v = *(const ushort8*)(h + (size_t)s * DIM + c0);
#pragma unroll
            for (int j = 0; j < 8; ++j) a0[j] += w * bf2f(v[j]);
        }
    }

    float v[8];
#pragma unroll
    for (int j = 0; j < 8; ++j) v[j] = a0[j] + a1[j];
    // combine the two halves (disjoint edge subsets, same 256 cols)
#pragma unroll
    for (int j = 0; j < 8; ++j) v[j] += __shfl_xor(v[j], 32);

    float4 b0 = *(const float4*)(bias + c0);
    float4 b1 = *(const float4*)(bias + c0 + 4);
    v[0] += b0.x; v[1] += b0.y; v[2] += b0.z; v[3] += b0.w;
    v[4] += b1.x; v[5] += b1.y; v[6] += b1.z; v[7] += b1.w;

    // LayerNorm: each 32-lane group holds all 256 cols exactly once
    float s1v = 0.f, s2v = 0.f;
#pragma unroll
    for (int j = 0; j < 8; ++j) { s1v += v[j]; s2v += v[j] * v[j]; }
#pragma unroll
    for (int off = 1; off < 32; off <<= 1) {
        s1v += __shfl_xor(s1v, off);
        s2v += __shfl_xor(s2v, off);
    }
    float mu = s1v * (1.0f / DIM);
    float var = s2v * (1.0f / DIM) - mu * mu;
    float rstd = rsqrtf(var + LN_EPS);

    float4 g0 = *(const float4*)(gamma + c0);
    float4 g1 = *(const float4*)(gamma + c0 + 4);
    float4 t0 = *(const float4*)(beta + c0);
    float4 t1 = *(const float4*)(beta + c0 + 4);
    float gg[8] = {g0.x, g0.y, g0.z, g0.w, g1.x, g1.y, g1.z, g1.w};
    float bb[8] = {t0.x, t0.y, t0.z, t0.w, t1.x, t1.y, t1.z, t1.w};
    if (half == 0) {
        ushort8 o;
#pragma unroll
        for (int j = 0; j < 8; ++j)
            o[j] = f2bf(fmaxf((v[j] - mu) * rstd * gg[j] + bb[j], 0.f));
        *(ushort8*)(out + (size_t)node * DIM + c0) = o;
    }
}

// -------------------- fused tail: pool (mean over graph) + FC + ReLU --------------------

__global__ __launch_bounds__(256) void k_tail(const ushort* __restrict__ x,
                                              const int* __restrict__ batch,
                                              const float* __restrict__ fcw,
                                              const float* __restrict__ fcb,
                                              float* __restrict__ out) {
    __shared__ float pl[DIM];
    __shared__ int bounds[2];
    int g = blockIdx.x;
    int t = threadIdx.x;
    if (t < 2) {
        int target = g + t;
        int lo = 0, hi = N_NODES;
        while (lo < hi) {
            int mid = (lo + hi) >> 1;
            if (batch[mid] < target) lo = mid + 1; else hi = mid;
        }
        bounds[t] = lo;
    }
    __syncthreads();
    int r0 = bounds[0], r1 = bounds[1];

    float s0 = 0.f, s1 = 0.f, s2 = 0.f, s3 = 0.f;
    int r = r0;
    for (; r + 3 < r1; r += 4) {
        s0 += bf2f(x[(size_t)(r + 0) * DIM + t]);
        s1 += bf2f(x[(size_t)(r + 1) * DIM + t]);
        s2 += bf2f(x[(size_t)(r + 2) * DIM + t]);
        s3 += bf2f(x[(size_t)(r + 3) * DIM + t]);
    }
    for (; r < r1; ++r) s0 += bf2f(x[(size_t)r * DIM + t]);
    float s = (s0 + s1) + (s2 + s3);
    pl[t] = s / fmaxf((float)(r1 - r0), 1.0f);
    __syncthreads();

    float acc = fcb[t];
    const float* wrow = fcw + (size_t)t * DIM;
    for (int k = 0; k < DIM; k += 4) {
        float4 w4 = *(const float4*)(wrow + k);
        acc += pl[k] * w4.x + pl[k + 1] * w4.y + pl[k + 2] * w4.z + pl[k + 3] * w4.w;
    }
    out[(size_t)g * DIM + t] = fmaxf(acc, 0.0f);
}

// -------------------- launch --------------------

extern "C" void kernel_launch(void* const* d_in, const int* in_sizes, int n_in,
                              void* d_out, int out_size, void* d_ws, size_t ws_size,
                              hipStream_t stream) {
    const float* x = (const float*)d_in[0];
    const int* ei = (const int*)d_in[1];
    const int* src = ei;
    const int* dst = ei + N_EDGES;
    const int* batch = (const int*)d_in[2];
    const float* W[3] = {(const float*)d_in[3], (const float*)d_in[7], (const float*)d_in[11]};
    const float* bs[3] = {(const float*)d_in[4], (const float*)d_in[8], (const float*)d_in[12]};
    const float* gs[3] = {(const float*)d_in[5], (const float*)d_in[9], (const float*)d_in[13]};
    const float* be[3] = {(const float*)d_in[6], (const float*)d_in[10], (const float*)d_in[14]};
    const float* fcw = (const float*)d_in[15];
    const float* fcb = (const float*)d_in[16];
    float* out = (float*)d_out;

    char* p = (char*)d_ws;
    auto alloc = [&](size_t bytes) {
        char* r = p;
        p += (bytes + 255) & ~(size_t)255;
        return r;
    };
    ushort* h       = (ushort*)alloc((size_t)N_NODES * DIM * 2);
    ushort* bufA    = (ushort*)alloc((size_t)N_NODES * DIM * 2);
    ushort* bufB    = (ushort*)alloc((size_t)N_NODES * DIM * 2);
    ushort* Wt      = (ushort*)alloc((size_t)3 * DIM * DIM * 2);
    int*   cnt     = (int*)alloc((size_t)N_NODES * 4);
    int*   row_ptr = (int*)alloc((size_t)(N_NODES + 1) * 4);
    int*   cursor  = (int*)alloc((size_t)N_NODES * 4);
    float* dinv    = (float*)alloc((size_t)N_NODES * 4);
    int2*  csr     = (int2*)alloc((size_t)N_EDGES * 8);
    int*   bsum    = (int*)alloc(256 * 4);

    hipMemsetAsync(cnt, 0, (size_t)N_NODES * 4, stream);

    const int TPB = 256;
    int gridN = (N_NODES + TPB - 1) / TPB;
    int gridE4 = (N_EDGES / 4 + TPB - 1) / TPB;

    k_wt3<<<48, TPB, 0, stream>>>(W[0], W[1], W[2], Wt);
    {
        int tot4 = N_NODES * DIM / 4;
        k_xcvt<<<(tot4 + TPB - 1) / TPB, TPB, 0, stream>>>(x, bufA);
    }

    k_hist<<<gridE4, TPB, 0, stream>>>(dst, cnt);
    k_scan1<<<NB1, TPB, 0, stream>>>(cnt, row_ptr, bsum);
    k_scan3<<<gridN, TPB, 0, stream>>>(bsum, cnt, row_ptr, cursor, dinv);
    k_scatter<<<gridE4, TPB, 0, stream>>>(src, dst, dinv, cursor, csr);

    ushort* cur = bufA;
    ushort* nxt = bufB;
    for (int l = 0; l < 3; ++l) {
        int gg = (N_NODES + GBM - 1) / GBM;
        k_gemm<<<gg, TPB, 0, stream>>>(cur, Wt + (size_t)l * DIM * DIM, h, N_NODES);
        k_agg_ln<<<N_NODES / 4, TPB, 0, stream>>>(h, row_ptr, csr, dinv,
                                                  bs[l], gs[l], be[l], nxt);
        ushort* tmp = cur; cur = nxt; nxt = tmp;
    }

    k_tail<<<N_GRAPHS, TPB, 0, stream>>>(cur, batch, fcw, fcb, out);
}

// Round 8
// 402.519 us; speedup vs baseline: 1.2394x; 1.0324x over previous
//
#include <hip/hip_runtime.h>
#include <hip/hip_bf16.h>

#define N_NODES 50000
#define N_EDGES 800000
#define N_GRAPHS 512
#define DIM 256
#define LN_EPS 1e-5f
#define CPAD 16   // counter stride (ints) = one 64B line per counter

typedef __attribute__((ext_vector_type(8))) short bf16x8;
typedef __attribute__((ext_vector_type(4))) float f32x4;
typedef __attribute__((ext_vector_type(8))) ushort ushort8;

__device__ __forceinline__ float bf2f(ushort u) {
    union { float f; unsigned int i; } c;
    c.i = ((unsigned int)u) << 16;
    return c.f;
}
__device__ __forceinline__ ushort f2bf(float f) {
    union { float f; unsigned int i; } c;
    c.f = f;
    unsigned int r = (c.i + 0x7fffu + ((c.i >> 16) & 1u)) >> 16;
    return (ushort)r;
}

// async global -> LDS, 16B per lane. lds base must be wave-uniform; HW adds lane*16.
__device__ __forceinline__ void async16(const ushort* g, ushort* l) {
    __builtin_amdgcn_global_load_lds(
        (const __attribute__((address_space(1))) unsigned int*)g,
        (__attribute__((address_space(3))) unsigned int*)l,
        16, 0, 0);
}

// -------------------- CSR build --------------------
// cnt/cursor are padded: counter i lives at [i*CPAD] (64B apart) to kill
// same-cacheline atomic serialization at the coherence point.

__global__ void k_hist(const int* __restrict__ dst, int* __restrict__ cnt) {
    int e = blockIdx.x * blockDim.x + threadIdx.x;
    const int HE = N_EDGES / 2;
    if (e < HE) {
        int d0 = dst[e];
        int d1 = dst[e + HE];
        atomicAdd(&cnt[d0 * CPAD], 1);
        atomicAdd(&cnt[d1 * CPAD], 1);
    }
}

__global__ __launch_bounds__(256) void k_scan1(const int* __restrict__ cnt,
                                               int* __restrict__ row_ptr,
                                               int* __restrict__ bsum) {
    __shared__ int sd[256];
    int t = threadIdx.x, b = blockIdx.x;
    int base = b * 2048 + t * 8;
    int v[8];
    int tot = 0;
#pragma unroll
    for (int j = 0; j < 8; ++j) {
        int i = base + j;
        int c = (i < N_NODES) ? cnt[i * CPAD] : 0;
        v[j] = tot;
        tot += c;
    }
    sd[t] = tot;
    __syncthreads();
    for (int off = 1; off < 256; off <<= 1) {
        int x = (t >= off) ? sd[t - off] : 0;
        __syncthreads();
        sd[t] += x;
        __syncthreads();
    }
    int excl = sd[t] - tot;
#pragma unroll
    for (int j = 0; j < 8; ++j) {
        int i = base + j;
        if (i < N_NODES) row_ptr[i] = excl + v[j];
    }
    if (t == 255) bsum[b] = sd[255];
}

// finalize row_ptr (adding serial prefix of <=25 block sums), init cursor, compute dinv
#define NB1 25
__global__ void k_scan3(const int* __restrict__ bsum, const int* __restrict__ cnt,
                        int* __restrict__ row_ptr, int* __restrict__ cursor,
                        float* __restrict__ dinv) {
    int i = blockIdx.x * blockDim.x + threadIdx.x;
    if (i < N_NODES) {
        int nb = i >> 11;
        int add = 0;
        for (int j = 0; j < nb; ++j) add += bsum[j];
        int v = row_ptr[i] + add;
        row_ptr[i] = v;
        cursor[i * CPAD] = v;
        dinv[i] = rsqrtf((float)cnt[i * CPAD] + 1.0f);
    }
    if (i == 0) row_ptr[N_NODES] = N_EDGES;
}

// CSR stores src only (4B/edge); weight recomputed in agg from dinv.
__global__ void k_scatter(const int* __restrict__ src, const int* __restrict__ dst,
                          int* __restrict__ cursor, int* __restrict__ csr_s) {
    int e = blockIdx.x * blockDim.x + threadIdx.x;
    if (e < N_EDGES) {
        int s = src[e], d = dst[e];
        int pos = atomicAdd(&cursor[d * CPAD], 1);
        csr_s[pos] = s;
    }
}

// -------------------- weight transpose + bf16 cast (all 3 layers, one launch) --------------------

__global__ __launch_bounds__(256) void k_wt3(const float* __restrict__ W0,
                                             const float* __restrict__ W1,
                                             const float* __restrict__ W2,
                                             ushort* __restrict__ Wt) {
    int l = blockIdx.x >> 4;
    const float* W = (l == 0) ? W0 : (l == 1) ? W1 : W2;
    ushort* o = Wt + (size_t)l * DIM * DIM;
    int t = threadIdx.x;
    int kbase = (blockIdx.x & 15) * 16;
    for (int kk = 0; kk < 16; ++kk) {
        int k = kbase + kk;
        o[(size_t)t * DIM + k] = f2bf(W[(size_t)k * DIM + t]);
    }
}

// -------------------- fp32 -> bf16 convert --------------------

__global__ __launch_bounds__(256) void k_xcvt(const float* __restrict__ x, ushort* __restrict__ o) {
    int i = blockIdx.x * blockDim.x + threadIdx.x;
    const size_t total4 = (size_t)N_NODES * DIM / 4;
    if ((size_t)i < total4) {
        float4 v = *(const float4*)(x + (size_t)i * 4);
        ushort4 u;
        u.x = f2bf(v.x); u.y = f2bf(v.y); u.z = f2bf(v.z); u.w = f2bf(v.w);
        *(ushort4*)(o + (size_t)i * 4) = u;
    }
}

// -------------------- bf16 MFMA GEMM: H[M x 256] = A[M x 256] @ W[256 x 256] --------------------
// Tile 128x256 (full width), BK=32, 4 waves, linear LDS + global_load_lds width-16.

#define GBM 128
#define GBK 32

__global__ __launch_bounds__(256) void k_gemm(const ushort* __restrict__ A,
                                              const ushort* __restrict__ Wt,
                                              ushort* __restrict__ H, int M) {
    __shared__ ushort As[GBM * GBK];        // 8 KB
    __shared__ ushort Bs[DIM * GBK];        // 16 KB
    int t = threadIdx.x;
    int lane = t & 63;
    int w = t >> 6;
    int wm = w >> 1, wn = w & 1;
    int bm0 = blockIdx.x * GBM;

    f32x4 acc[4][8];
#pragma unroll
    for (int m = 0; m < 4; ++m)
#pragma unroll
        for (int n = 0; n < 8; ++n) acc[m][n] = (f32x4)0.0f;

    int fr = lane & 15;
    int fq = lane >> 4;
    int lr = lane >> 2;
    int lc = (lane & 3) * 8;

    for (int k0 = 0; k0 < DIM; k0 += GBK) {
#pragma unroll
        for (int p = 0; p < 2; ++p) {
            int rb = (w + p * 4) * 16;
            int ga = bm0 + rb + lr;
            if (ga > M - 1) ga = M - 1;
            async16(A + (size_t)ga * DIM + k0 + lc, &As[rb * GBK]);
        }
#pragma unroll
        for (int p = 0; p < 4; ++p) {
            int rb = (w * 4 + p) * 16;
            async16(Wt + (size_t)(rb + lr) * DIM + k0 + lc, &Bs[rb * GBK]);
        }
        __syncthreads();
        bf16x8 af[4], bfv[8];
#pragma unroll
        for (int m = 0; m < 4; ++m)
            af[m] = *(const bf16x8*)&As[(wm * 64 + m * 16 + fr) * GBK + fq * 8];
#pragma unroll
        for (int n = 0; n < 8; ++n)
            bfv[n] = *(const bf16x8*)&Bs[(wn * 128 + n * 16 + fr) * GBK + fq * 8];
#pragma unroll
        for (int m = 0; m < 4; ++m)
#pragma unroll
            for (int n = 0; n < 8; ++n)
                acc[m][n] = __builtin_amdgcn_mfma_f32_16x16x32_bf16(af[m], bfv[n], acc[m][n], 0, 0, 0);
        __syncthreads();
    }
    // D row = (lane>>4)*4 + j, col = lane&15  [m89-verified]
#pragma unroll
    for (int m = 0; m < 4; ++m) {
        int row0 = bm0 + wm * 64 + m * 16 + fq * 4;
#pragma unroll
        for (int n = 0; n < 8; ++n) {
            int col = wn * 128 + n * 16 + fr;
#pragma unroll
            for (int j = 0; j < 4; ++j) {
                int row = row0 + j;
                if (row < M) H[(size_t)row * DIM + col] = f2bf(acc[m][n][j]);
            }
        }
    }
}

// -------------------- aggregation + bias + LayerNorm + ReLU (bf16 in/out) --------------------
// 4 nodes/block, 1 wave/node, two 32-lane halves each gathering full 512B rows
// (ushort8/lane). Metadata: coalesced csr_s batch + coalesced dinv gather +
// __shfl broadcast; weight w = dinv[node]*dinv[s] recomputed on the fly.

__global__ __launch_bounds__(256) void k_agg_ln(const ushort* __restrict__ h,
                                                const int* __restrict__ rp,
                                                const int* __restrict__ csr_s,
                                                const float* __restrict__ dinv,
                                                const float* __restrict__ bias,
                                                const float* __restrict__ gamma,
                                                const float* __restrict__ beta,
                                                ushort* __restrict__ out) {
    int node = (blockIdx.x << 2) + (threadIdx.x >> 6);
    int lane = threadIdx.x & 63;
    int half = lane >> 5;
    int c0 = (lane & 31) << 3;   // 8 cols per lane, 32 lanes cover the row

    float a0[8], a1[8];
#pragma unroll
    for (int j = 0; j < 8; ++j) { a0[j] = 0.f; a1[j] = 0.f; }

    float di = dinv[node];
    // self-loop term (lower half only)
    if (half == 0) {
        float sw = di * di;
        ushort8 sv = *(const ushort8*)(h + (size_t)node * DIM + c0);
#pragma unroll
        for (int j = 0; j < 8; ++j) a0[j] = sw * bf2f(sv[j]);
    }

    int e0 = rp[node], e1 = rp[node + 1];
    for (int eb = e0; eb < e1; eb += 64) {
        int idx = eb + lane;
        if (idx > N_EDGES - 1) idx = N_EDGES - 1;
        int sl = csr_s[idx];              // lane L holds src of edge eb+L
        float pl_ = dinv[sl];             // coalesced-issued gather, L2-resident
        int n = e1 - eb;
        if (n > 64) n = 64;
        // this half processes edges jj ≡ half (mod 2), quad-unrolled
        int jj = half;
        for (; jj + 6 < n; jj += 8) {
            int s0 = __shfl(sl, jj);
            float w0 = di * __shfl(pl_, jj);
            int s1 = __shfl(sl, jj + 2);
            float w1 = di * __shfl(pl_, jj + 2);
            int s2 = __shfl(sl, jj + 4);
            float w2 = di * __shfl(pl_, jj + 4);
            int s3 = __shfl(sl, jj + 6);
            float w3 = di * __shfl(pl_, jj + 6);
            ushort8 v0 = *(const ushort8*)(h + (size_t)s0 * DIM + c0);
            ushort8 v1 = *(const ushort8*)(h + (size_t)s1 * DIM + c0);
            ushort8 v2 = *(const ushort8*)(h + (size_t)s2 * DIM + c0);
            ushort8 v3 = *(const ushort8*)(h + (size_t)s3 * DIM + c0);
#pragma unroll
            for (int j = 0; j < 8; ++j) a0[j] += w0 * bf2f(v0[j]);
#pragma unroll
            for (int j = 0; j < 8; ++j) a1[j] += w1 * bf2f(v1[j]);
#pragma unroll
            for (int j = 0; j < 8; ++j) a0[j] += w2 * bf2f(v2[j]);
#pragma unroll
            for (int j = 0; j < 8; ++j) a1[j] += w3 * bf2f(v3[j]);
        }
        for (; jj + 2 < n; jj += 4) {
            int s0 = __shfl(sl, jj);
            float w0 = di * __shfl(pl_, jj);
            int s1 = __shfl(sl, jj + 2);
            float w1 = di * __shfl(pl_, jj + 2);
            ushort8 v0 = *(const ushort8*)(h + (size_t)s0 * DIM + c0);
            ushort8 v1 = *(const ushort8*)(h + (size_t)s1 * DIM + c0);
#pragma unroll
            for (int j = 0; j < 8; ++j) a0[j] += w0 * bf2f(v0[j]);
#pragma unroll
            for (int j = 0; j < 8; ++j) a1[j] += w1 * bf2f(v1[j]);
        }
        if (jj < n) {
            int s = __shfl(sl, jj);
            float w = di * __shfl(pl_, jj);
            ushort8 v = *(const ushort8*)(h + (size_t)s * DIM + c0);
#pragma unroll
            for (int j = 0; j < 8; ++j) a0[j] += w * bf2f(v[j]);
        }
    }

    float v[8];
#pragma unroll
    for (int j = 0; j < 8; ++j) v[j] = a0[j] + a1[j];
    // combine the two halves (disjoint edge subsets, same 256 cols)
#pragma unroll
    for (int j = 0; j < 8; ++j) v[j] += __shfl_xor(v[j], 32);

    float4 b0 = *(const float4*)(bias + c0);
    float4 b1 = *(const float4*)(bias + c0 + 4);
    v[0] += b0.x; v[1] += b0.y; v[2] += b0.z; v[3] += b0.w;
    v[4] += b1.x; v[5] += b1.y; v[6] += b1.z; v[7] += b1.w;

    // LayerNorm: each 32-lane group holds all 256 cols exactly once
    float s1v = 0.f, s2v = 0.f;
#pragma unroll
    for (int j = 0; j < 8; ++j) { s1v += v[j]; s2v += v[j] * v[j]; }
#pragma unroll
    for (int off = 1; off < 32; off <<= 1) {
        s1v += __shfl_xor(s1v, off);
        s2v += __shfl_xor(s2v, off);
    }
    float mu = s1v * (1.0f / DIM);
    float var = s2v * (1.0f / DIM) - mu * mu;
    float rstd = rsqrtf(var + LN_EPS);

    float4 g0 = *(const float4*)(gamma + c0);
    float4 g1 = *(const float4*)(gamma + c0 + 4);
    float4 t0 = *(const float4*)(beta + c0);
    float4 t1 = *(const float4*)(beta + c0 + 4);
    float gg[8] = {g0.x, g0.y, g0.z, g0.w, g1.x, g1.y, g1.z, g1.w};
    float bb[8] = {t0.x, t0.y, t0.z, t0.w, t1.x, t1.y, t1.z, t1.w};
    if (half == 0) {
        ushort8 o;
#pragma unroll
        for (int j = 0; j < 8; ++j)
            o[j] = f2bf(fmaxf((v[j] - mu) * rstd * gg[j] + bb[j], 0.f));
        *(ushort8*)(out + (size_t)node * DIM + c0) = o;
    }
}

// -------------------- fused tail: pool (mean over graph) + FC + ReLU --------------------

__global__ __launch_bounds__(256) void k_tail(const ushort* __restrict__ x,
                                              const int* __restrict__ batch,
                                              const float* __restrict__ fcw,
                                              const float* __restrict__ fcb,
                                              float* __restrict__ out) {
    __shared__ float pl[DIM];
    __shared__ int bounds[2];
    int g = blockIdx.x;
    int t = threadIdx.x;
    if (t < 2) {
        int target = g + t;
        int lo = 0, hi = N_NODES;
        while (lo < hi) {
            int mid = (lo + hi) >> 1;
            if (batch[mid] < target) lo = mid + 1; else hi = mid;
        }
        bounds[t] = lo;
    }
    __syncthreads();
    int r0 = bounds[0], r1 = bounds[1];

    float s0 = 0.f, s1 = 0.f, s2 = 0.f, s3 = 0.f;
    int r = r0;
    for (; r + 3 < r1; r += 4) {
        s0 += bf2f(x[(size_t)(r + 0) * DIM + t]);
        s1 += bf2f(x[(size_t)(r + 1) * DIM + t]);
        s2 += bf2f(x[(size_t)(r + 2) * DIM + t]);
        s3 += bf2f(x[(size_t)(r + 3) * DIM + t]);
    }
    for (; r < r1; ++r) s0 += bf2f(x[(size_t)r * DIM + t]);
    float s = (s0 + s1) + (s2 + s3);
    pl[t] = s / fmaxf((float)(r1 - r0), 1.0f);
    __syncthreads();

    float acc = fcb[t];
    const float* wrow = fcw + (size_t)t * DIM;
    for (int k = 0; k < DIM; k += 4) {
        float4 w4 = *(const float4*)(wrow + k);
        acc += pl[k] * w4.x + pl[k + 1] * w4.y + pl[k + 2] * w4.z + pl[k + 3] * w4.w;
    }
    out[(size_t)g * DIM + t] = fmaxf(acc, 0.0f);
}

// -------------------- launch --------------------

extern "C" void kernel_launch(void* const* d_in, const int* in_sizes, int n_in,
                              void* d_out, int out_size, void* d_ws, size_t ws_size,
                              hipStream_t stream) {
    const float* x = (const float*)d_in[0];
    const int* ei = (const int*)d_in[1];
    const int* src = ei;
    const int* dst = ei + N_EDGES;
    const int* batch = (const int*)d_in[2];
    const float* W[3] = {(const float*)d_in[3], (const float*)d_in[7], (const float*)d_in[11]};
    const float* bs[3] = {(const float*)d_in[4], (const float*)d_in[8], (const float*)d_in[12]};
    const float* gs[3] = {(const float*)d_in[5], (const float*)d_in[9], (const float*)d_in[13]};
    const float* be[3] = {(const float*)d_in[6], (const float*)d_in[10], (const float*)d_in[14]};
    const float* fcw = (const float*)d_in[15];
    const float* fcb = (const float*)d_in[16];
    float* out = (float*)d_out;

    char* p = (char*)d_ws;
    auto alloc = [&](size_t bytes) {
        char* r = p;
        p += (bytes + 255) & ~(size_t)255;
        return r;
    };
    ushort* h       = (ushort*)alloc((size_t)N_NODES * DIM * 2);
    ushort* bufA    = (ushort*)alloc((size_t)N_NODES * DIM * 2);
    ushort* bufB    = (ushort*)alloc((size_t)N_NODES * DIM * 2);
    ushort* Wt      = (ushort*)alloc((size_t)3 * DIM * DIM * 2);
    int*   cnt     = (int*)alloc((size_t)N_NODES * CPAD * 4);
    int*   cursor  = (int*)alloc((size_t)N_NODES * CPAD * 4);
    int*   row_ptr = (int*)alloc((size_t)(N_NODES + 1) * 4);
    float* dinv    = (float*)alloc((size_t)N_NODES * 4);
    int*   csr_s   = (int*)alloc((size_t)N_EDGES * 4);
    int*   bsum    = (int*)alloc(256 * 4);

    hipMemsetAsync(cnt, 0, (size_t)N_NODES * CPAD * 4, stream);

    const int TPB = 256;
    int gridN = (N_NODES + TPB - 1) / TPB;
    int gridE = (N_EDGES + TPB - 1) / TPB;
    int gridE2 = (N_EDGES / 2 + TPB - 1) / TPB;

    k_wt3<<<48, TPB, 0, stream>>>(W[0], W[1], W[2], Wt);
    {
        int tot4 = N_NODES * DIM / 4;
        k_xcvt<<<(tot4 + TPB - 1) / TPB, TPB, 0, stream>>>(x, bufA);
    }

    k_hist<<<gridE2, TPB, 0, stream>>>(dst, cnt);
    k_scan1<<<NB1, TPB, 0, stream>>>(cnt, row_ptr, bsum);
    k_scan3<<<gridN, TPB, 0, stream>>>(bsum, cnt, row_ptr, cursor, dinv);
    k_scatter<<<gridE, TPB, 0, stream>>>(src, dst, cursor, csr_s);

    ushort* cur = bufA;
    ushort* nxt = bufB;
    for (int l = 0; l < 3; ++l) {
        int gg = (N_NODES + GBM - 1) / GBM;
        k_gemm<<<gg, TPB, 0, stream>>>(cur, Wt + (size_t)l * DIM * DIM, h, N_NODES);
        k_agg_ln<<<N_NODES / 4, TPB, 0, stream>>>(h, row_ptr, csr_s, dinv,
                                                  bs[l], gs[l], be[l], nxt);
        ushort* tmp = cur; cur = nxt; nxt = tmp;
    }

    k_tail<<<N_GRAPHS, TPB, 0, stream>>>(cur, batch, fcw, fcb, out);
}

// Round 9
// 371.378 us; speedup vs baseline: 1.3433x; 1.0839x over previous
//
#include <hip/hip_runtime.h>
#include <hip/hip_bf16.h>

#define N_NODES 50000
#define N_EDGES 800000
#define N_GRAPHS 512
#define DIM 256
#define LN_EPS 1e-5f
#define CPAD 16   // counter stride (ints) = one 64B line per counter

typedef __attribute__((ext_vector_type(8))) short bf16x8;
typedef __attribute__((ext_vector_type(4))) float f32x4;
typedef __attribute__((ext_vector_type(8))) ushort ushort8;

__device__ __forceinline__ float bf2f(ushort u) {
    union { float f; unsigned int i; } c;
    c.i = ((unsigned int)u) << 16;
    return c.f;
}
__device__ __forceinline__ ushort f2bf(float f) {
    union { float f; unsigned int i; } c;
    c.f = f;
    unsigned int r = (c.i + 0x7fffu + ((c.i >> 16) & 1u)) >> 16;
    return (ushort)r;
}

// async global -> LDS, 16B per lane. lds base must be wave-uniform; HW adds lane*16.
__device__ __forceinline__ void async16(const ushort* g, ushort* l) {
    __builtin_amdgcn_global_load_lds(
        (const __attribute__((address_space(1))) unsigned int*)g,
        (__attribute__((address_space(3))) unsigned int*)l,
        16, 0, 0);
}

// -------------------- CSR build --------------------
// cnt/cursor padded: counter i at [i*CPAD] (64B apart) — kills same-line atomic serialization.

__global__ void k_hist(const int* __restrict__ dst, int* __restrict__ cnt) {
    int e = blockIdx.x * blockDim.x + threadIdx.x;
    const int HE = N_EDGES / 2;
    if (e < HE) {
        int d0 = dst[e];
        int d1 = dst[e + HE];
        atomicAdd(&cnt[d0 * CPAD], 1);
        atomicAdd(&cnt[d1 * CPAD], 1);
    }
}

__global__ __launch_bounds__(256) void k_scan1(const int* __restrict__ cnt,
                                               int* __restrict__ row_ptr,
                                               int* __restrict__ bsum) {
    __shared__ int sd[256];
    int t = threadIdx.x, b = blockIdx.x;
    int base = b * 2048 + t * 8;
    int v[8];
    int tot = 0;
#pragma unroll
    for (int j = 0; j < 8; ++j) {
        int i = base + j;
        int c = (i < N_NODES) ? cnt[i * CPAD] : 0;
        v[j] = tot;
        tot += c;
    }
    sd[t] = tot;
    __syncthreads();
    for (int off = 1; off < 256; off <<= 1) {
        int x = (t >= off) ? sd[t - off] : 0;
        __syncthreads();
        sd[t] += x;
        __syncthreads();
    }
    int excl = sd[t] - tot;
#pragma unroll
    for (int j = 0; j < 8; ++j) {
        int i = base + j;
        if (i < N_NODES) row_ptr[i] = excl + v[j];
    }
    if (t == 255) bsum[b] = sd[255];
}

// finalize row_ptr (adding serial prefix of <=25 block sums), init cursor, compute dinv
#define NB1 25
__global__ void k_scan3(const int* __restrict__ bsum, const int* __restrict__ cnt,
                        int* __restrict__ row_ptr, int* __restrict__ cursor,
                        float* __restrict__ dinv) {
    int i = blockIdx.x * blockDim.x + threadIdx.x;
    if (i < N_NODES) {
        int nb = i >> 11;
        int add = 0;
        for (int j = 0; j < nb; ++j) add += bsum[j];
        int v = row_ptr[i] + add;
        row_ptr[i] = v;
        cursor[i * CPAD] = v;
        dinv[i] = rsqrtf((float)cnt[i * CPAD] + 1.0f);
    }
    if (i == 0) row_ptr[N_NODES] = N_EDGES;
}

// CSR stores src only (4B/edge); weight recomputed in agg from dinv.
__global__ void k_scatter(const int* __restrict__ src, const int* __restrict__ dst,
                          int* __restrict__ cursor, int* __restrict__ csr_s) {
    int e = blockIdx.x * blockDim.x + threadIdx.x;
    if (e < N_EDGES) {
        int s = src[e], d = dst[e];
        int pos = atomicAdd(&cursor[d * CPAD], 1);
        csr_s[pos] = s;
    }
}

// -------------------- weight transpose + bf16 cast (all 3 layers, one launch) --------------------

__global__ __launch_bounds__(256) void k_wt3(const float* __restrict__ W0,
                                             const float* __restrict__ W1,
                                             const float* __restrict__ W2,
                                             ushort* __restrict__ Wt) {
    int l = blockIdx.x >> 4;
    const float* W = (l == 0) ? W0 : (l == 1) ? W1 : W2;
    ushort* o = Wt + (size_t)l * DIM * DIM;
    int t = threadIdx.x;
    int kbase = (blockIdx.x & 15) * 16;
    for (int kk = 0; kk < 16; ++kk) {
        int k = kbase + kk;
        o[(size_t)t * DIM + k] = f2bf(W[(size_t)k * DIM + t]);
    }
}

// -------------------- fp32 -> bf16 convert --------------------

__global__ __launch_bounds__(256) void k_xcvt(const float* __restrict__ x, ushort* __restrict__ o) {
    int i = blockIdx.x * blockDim.x + threadIdx.x;
    const size_t total4 = (size_t)N_NODES * DIM / 4;
    if ((size_t)i < total4) {
        float4 v = *(const float4*)(x + (size_t)i * 4);
        ushort4 u;
        u.x = f2bf(v.x); u.y = f2bf(v.y); u.z = f2bf(v.z); u.w = f2bf(v.w);
        *(ushort4*)(o + (size_t)i * 4) = u;
    }
}

// -------------------- bf16 MFMA GEMM: H[M x 256] = A[M x 256] @ W[256 x 256] --------------------
// Tile 128x256, BK=32, 8 waves (512 thr): wave = 32 rows x 128 cols, acc 64 VGPR.
// Linear LDS + global_load_lds width-16 staging.

#define GBM 128
#define GBK 32

__global__ __launch_bounds__(512) void k_gemm(const ushort* __restrict__ A,
                                              const ushort* __restrict__ Wt,
                                              ushort* __restrict__ H, int M) {
    __shared__ ushort As[GBM * GBK];        // 8 KB
    __shared__ ushort Bs[DIM * GBK];        // 16 KB
    int t = threadIdx.x;
    int lane = t & 63;
    int w = t >> 6;                         // 0..7
    int wm = w >> 1, wn = w & 1;            // wave tile: rows wm*32..+31, cols wn*128..+127
    int bm0 = blockIdx.x * GBM;

    f32x4 acc[2][8];
#pragma unroll
    for (int m = 0; m < 2; ++m)
#pragma unroll
        for (int n = 0; n < 8; ++n) acc[m][n] = (f32x4)0.0f;

    int fr = lane & 15;
    int fq = lane >> 4;
    int lr = lane >> 2;
    int lc = (lane & 3) * 8;

    for (int k0 = 0; k0 < DIM; k0 += GBK) {
        // A: 8 chunks of 16 rows; wave w stages chunk w
        {
            int rb = w * 16;
            int ga = bm0 + rb + lr;
            if (ga > M - 1) ga = M - 1;
            async16(A + (size_t)ga * DIM + k0 + lc, &As[rb * GBK]);
        }
        // B: 16 chunks; wave w stages chunks 2w, 2w+1
#pragma unroll
        for (int p = 0; p < 2; ++p) {
            int rb = w * 32 + p * 16;
            async16(Wt + (size_t)(rb + lr) * DIM + k0 + lc, &Bs[rb * GBK]);
        }
        __syncthreads();
        bf16x8 af[2], bfv[8];
#pragma unroll
        for (int m = 0; m < 2; ++m)
            af[m] = *(const bf16x8*)&As[(wm * 32 + m * 16 + fr) * GBK + fq * 8];
#pragma unroll
        for (int n = 0; n < 8; ++n)
            bfv[n] = *(const bf16x8*)&Bs[(wn * 128 + n * 16 + fr) * GBK + fq * 8];
#pragma unroll
        for (int m = 0; m < 2; ++m)
#pragma unroll
            for (int n = 0; n < 8; ++n)
                acc[m][n] = __builtin_amdgcn_mfma_f32_16x16x32_bf16(af[m], bfv[n], acc[m][n], 0, 0, 0);
        __syncthreads();
    }
    // D row = (lane>>4)*4 + j, col = lane&15  [m89-verified]
#pragma unroll
    for (int m = 0; m < 2; ++m) {
        int row0 = bm0 + wm * 32 + m * 16 + fq * 4;
#pragma unroll
        for (int n = 0; n < 8; ++n) {
            int col = wn * 128 + n * 16 + fr;
#pragma unroll
            for (int j = 0; j < 4; ++j) {
                int row = row0 + j;
                if (row < M) H[(size_t)row * DIM + col] = f2bf(acc[m][n][j]);
            }
        }
    }
}

// -------------------- aggregation + bias + LayerNorm + ReLU (bf16 in/out) --------------------
// 8 nodes/block, 2 nodes/wave: each 32-lane half owns ONE full node (all its edges,
// self-loop, LN, store). 8 cols/lane. Metadata: coalesced 32-edge csr_s batch +
// dinv gather + width-32 __shfl broadcast. Quad-unrolled gathers (4 in flight/half).

__global__ __launch_bounds__(256) void k_agg_ln(const ushort* __restrict__ h,
                                                const int* __restrict__ rp,
                                                const int* __restrict__ csr_s,
                                                const float* __restrict__ dinv,
                                                const float* __restrict__ bias,
                                                const float* __restrict__ gamma,
                                                const float* __restrict__ beta,
                                                ushort* __restrict__ out) {
    int wv = threadIdx.x >> 6;
    int lane = threadIdx.x & 63;
    int half = lane >> 5;
    int l32 = lane & 31;
    int node = (blockIdx.x << 3) + (wv << 1) + half;   // each half owns this node
    int c0 = l32 << 3;                                  // 8 cols/lane, 32 lanes = 256 cols

    float a0[8], a1[8];
    float di = dinv[node];
    {
        float sw = di * di;
        ushort8 sv = *(const ushort8*)(h + (size_t)node * DIM + c0);
#pragma unroll
        for (int j = 0; j < 8; ++j) a0[j] = sw * bf2f(sv[j]);
    }
#pragma unroll
    for (int j = 0; j < 8; ++j) a1[j] = 0.f;

    int e0 = rp[node], e1 = rp[node + 1];
    for (int eb = e0; eb < e1; eb += 32) {
        int idx = eb + l32;
        if (idx > N_EDGES - 1) idx = N_EDGES - 1;
        int sl = csr_s[idx];              // lane l32 holds src of edge eb+l32 (this half's node)
        float pl_ = dinv[sl];             // L2-resident gather
        int n = e1 - eb;
        if (n > 32) n = 32;
        int jj = 0;
        for (; jj + 3 < n; jj += 4) {
            int s0 = __shfl(sl, jj, 32);
            float w0 = di * __shfl(pl_, jj, 32);
            int s1 = __shfl(sl, jj + 1, 32);
            float w1 = di * __shfl(pl_, jj + 1, 32);
            int s2 = __shfl(sl, jj + 2, 32);
            float w2 = di * __shfl(pl_, jj + 2, 32);
            int s3 = __shfl(sl, jj + 3, 32);
            float w3 = di * __shfl(pl_, jj + 3, 32);
            ushort8 v0 = *(const ushort8*)(h + (size_t)s0 * DIM + c0);
            ushort8 v1 = *(const ushort8*)(h + (size_t)s1 * DIM + c0);
            ushort8 v2 = *(const ushort8*)(h + (size_t)s2 * DIM + c0);
            ushort8 v3 = *(const ushort8*)(h + (size_t)s3 * DIM + c0);
#pragma unroll
            for (int j = 0; j < 8; ++j) a0[j] += w0 * bf2f(v0[j]);
#pragma unroll
            for (int j = 0; j < 8; ++j) a1[j] += w1 * bf2f(v1[j]);
#pragma unroll
            for (int j = 0; j < 8; ++j) a0[j] += w2 * bf2f(v2[j]);
#pragma unroll
            for (int j = 0; j < 8; ++j) a1[j] += w3 * bf2f(v3[j]);
        }
        for (; jj < n; ++jj) {
            int s = __shfl(sl, jj, 32);
            float w = di * __shfl(pl_, jj, 32);
            ushort8 v = *(const ushort8*)(h + (size_t)s * DIM + c0);
#pragma unroll
            for (int j = 0; j < 8; ++j) a0[j] += w * bf2f(v[j]);
        }
    }

    float v[8];
#pragma unroll
    for (int j = 0; j < 8; ++j) v[j] = a0[j] + a1[j];

    float4 b0 = *(const float4*)(bias + c0);
    float4 b1 = *(const float4*)(bias + c0 + 4);
    v[0] += b0.x; v[1] += b0.y; v[2] += b0.z; v[3] += b0.w;
    v[4] += b1.x; v[5] += b1.y; v[6] += b1.z; v[7] += b1.w;

    // LayerNorm over this half's 32 lanes x 8 = 256 cols
    float s1v = 0.f, s2v = 0.f;
#pragma unroll
    for (int j = 0; j < 8; ++j) { s1v += v[j]; s2v += v[j] * v[j]; }
#pragma unroll
    for (int off = 1; off < 32; off <<= 1) {
        s1v += __shfl_xor(s1v, off);
        s2v += __shfl_xor(s2v, off);
    }
    float mu = s1v * (1.0f / DIM);
    float var = s2v * (1.0f / DIM) - mu * mu;
    float rstd = rsqrtf(var + LN_EPS);

    float4 g0 = *(const float4*)(gamma + c0);
    float4 g1 = *(const float4*)(gamma + c0 + 4);
    float4 t0 = *(const float4*)(beta + c0);
    float4 t1 = *(const float4*)(beta + c0 + 4);
    float gg[8] = {g0.x, g0.y, g0.z, g0.w, g1.x, g1.y, g1.z, g1.w};
    float bb[8] = {t0.x, t0.y, t0.z, t0.w, t1.x, t1.y, t1.z, t1.w};
    ushort8 o;
#pragma unroll
    for (int j = 0; j < 8; ++j)
        o[j] = f2bf(fmaxf((v[j] - mu) * rstd * gg[j] + bb[j], 0.f));
    *(ushort8*)(out + (size_t)node * DIM + c0) = o;
}

// -------------------- fused tail: pool (mean over graph) + FC + ReLU --------------------

__global__ __launch_bounds__(256) void k_tail(const ushort* __restrict__ x,
                                              const int* __restrict__ batch,
                                              const float* __restrict__ fcw,
                                              const float* __restrict__ fcb,
                                              float* __restrict__ out) {
    __shared__ float pl[DIM];
    __shared__ int bounds[2];
    int g = blockIdx.x;
    int t = threadIdx.x;
    if (t < 2) {
        int target = g + t;
        int lo = 0, hi = N_NODES;
        while (lo < hi) {
            int mid = (lo + hi) >> 1;
            if (batch[mid] < target) lo = mid + 1; else hi = mid;
        }
        bounds[t] = lo;
    }
    __syncthreads();
    int r0 = bounds[0], r1 = bounds[1];

    float s0 = 0.f, s1 = 0.f, s2 = 0.f, s3 = 0.f;
    int r = r0;
    for (; r + 3 < r1; r += 4) {
        s0 += bf2f(x[(size_t)(r + 0) * DIM + t]);
        s1 += bf2f(x[(size_t)(r + 1) * DIM + t]);
        s2 += bf2f(x[(size_t)(r + 2) * DIM + t]);
        s3 += bf2f(x[(size_t)(r + 3) * DIM + t]);
    }
    for (; r < r1; ++r) s0 += bf2f(x[(size_t)r * DIM + t]);
    float s = (s0 + s1) + (s2 + s3);
    pl[t] = s / fmaxf((float)(r1 - r0), 1.0f);
    __syncthreads();

    float acc = fcb[t];
    const float* wrow = fcw + (size_t)t * DIM;
    for (int k = 0; k < DIM; k += 4) {
        float4 w4 = *(const float4*)(wrow + k);
        acc += pl[k] * w4.x + pl[k + 1] * w4.y + pl[k + 2] * w4.z + pl[k + 3] * w4.w;
    }
    out[(size_t)g * DIM + t] = fmaxf(acc, 0.0f);
}

// -------------------- launch --------------------

extern "C" void kernel_launch(void* const* d_in, const int* in_sizes, int n_in,
                              void* d_out, int out_size, void* d_ws, size_t ws_size,
                              hipStream_t stream) {
    const float* x = (const float*)d_in[0];
    const int* ei = (const int*)d_in[1];
    const int* src = ei;
    const int* dst = ei + N_EDGES;
    const int* batch = (const int*)d_in[2];
    const float* W[3] = {(const float*)d_in[3], (const float*)d_in[7], (const float*)d_in[11]};
    const float* bs[3] = {(const float*)d_in[4], (const float*)d_in[8], (const float*)d_in[12]};
    const float* gs[3] = {(const float*)d_in[5], (const float*)d_in[9], (const float*)d_in[13]};
    const float* be[3] = {(const float*)d_in[6], (const float*)d_in[10], (const float*)d_in[14]};
    const float* fcw = (const float*)d_in[15];
    const float* fcb = (const float*)d_in[16];
    float* out = (float*)d_out;

    char* p = (char*)d_ws;
    auto alloc = [&](size_t bytes) {
        char* r = p;
        p += (bytes + 255) & ~(size_t)255;
        return r;
    };
    ushort* h       = (ushort*)alloc((size_t)N_NODES * DIM * 2);
    ushort* bufA    = (ushort*)alloc((size_t)N_NODES * DIM * 2);
    ushort* bufB    = (ushort*)alloc((size_t)N_NODES * DIM * 2);
    ushort* Wt      = (ushort*)alloc((size_t)3 * DIM * DIM * 2);
    int*   cnt     = (int*)alloc((size_t)N_NODES * CPAD * 4);
    int*   cursor  = (int*)alloc((size_t)N_NODES * CPAD * 4);
    int*   row_ptr = (int*)alloc((size_t)(N_NODES + 1) * 4);
    float* dinv    = (float*)alloc((size_t)N_NODES * 4);
    int*   csr_s   = (int*)alloc((size_t)N_EDGES * 4);
    int*   bsum    = (int*)alloc(256 * 4);

    hipMemsetAsync(cnt, 0, (size_t)N_NODES * CPAD * 4, stream);

    const int TPB = 256;
    int gridN = (N_NODES + TPB - 1) / TPB;
    int gridE = (N_EDGES + TPB - 1) / TPB;
    int gridE2 = (N_EDGES / 2 + TPB - 1) / TPB;

    k_wt3<<<48, TPB, 0, stream>>>(W[0], W[1], W[2], Wt);
    {
        int tot4 = N_NODES * DIM / 4;
        k_xcvt<<<(tot4 + TPB - 1) / TPB, TPB, 0, stream>>>(x, bufA);
    }

    k_hist<<<gridE2, TPB, 0, stream>>>(dst, cnt);
    k_scan1<<<NB1, TPB, 0, stream>>>(cnt, row_ptr, bsum);
    k_scan3<<<gridN, TPB, 0, stream>>>(bsum, cnt, row_ptr, cursor, dinv);
    k_scatter<<<gridE, TPB, 0, stream>>>(src, dst, cursor, csr_s);

    ushort* cur = bufA;
    ushort* nxt = bufB;
    for (int l = 0; l < 3; ++l) {
        int gg = (N_NODES + GBM - 1) / GBM;
        k_gemm<<<gg, 512, 0, stream>>>(cur, Wt + (size_t)l * DIM * DIM, h, N_NODES);
        k_agg_ln<<<N_NODES / 8, TPB, 0, stream>>>(h, row_ptr, csr_s, dinv,
                                                  bs[l], gs[l], be[l], nxt);
        ushort* tmp = cur; cur = nxt; nxt = tmp;
    }

    k_tail<<<N_GRAPHS, TPB, 0, stream>>>(cur, batch, fcw, fcb, out);
}